// Round 6
// baseline (7781.279 us; speedup 1.0000x reference)
//
#include <hip/hip_runtime.h>
#include <hip/hip_bf16.h>

// MoBA attention, MI355X gfx950 — ROUND 6: R3 pipeline (f32 inputs — CORRECT,
// per in_npz size 78.66MB = f32) with the one real bug fixed: d_out is FLOAT32,
// not bf16. R1/R3's absmax 3.797 == max|N(0,2*0.45^2)| over 4M = comparing
// ref[j] vs out[2j+1], the signature of bf16 shorts written into an f32 buffer.
// Gate path f64 end-to-end (matches f64 np golden top-k exactly); attention f32.

// ---------------- RoPE table: pure f64 phase ----------------
__global__ __launch_bounds__(256) void rtab_k(double2* __restrict__ tab){
  const int i = blockIdx.x*256 + threadIdx.x;      // 2048*32
  if (i >= 2048*32) return;
  const int d2 = i & 31, s = i >> 5;
  const double invf = 1.0 / pow(10000.0, (double)d2 / 32.0);
  const double ph = (double)s * invf;
  tab[i] = make_double2(cos(ph), sin(ph));
}

// ---------------- naive tiled GEMM: C[M,N] = A[M,K] * B[N,K]^T ----------------
// 64x64 tile, 256 threads, 4x4 per thread, BK=16. TACC = float|double.
// OUT: 0=f32, 2=f64.
template<typename TACC, int OUT>
__global__ __launch_bounds__(256) void gemm_naive(
    const float* __restrict__ A,
    const float* __restrict__ B0, const float* __restrict__ B1,
    void* __restrict__ C0, void* __restrict__ C1,
    int M, int N, int K)
{
  __shared__ float As[16][64];
  __shared__ float Bs[16][64];
  const int z = blockIdx.z;
  const float* B = z ? B1 : B0;
  void* C = z ? C1 : C0;
  const int tid = threadIdx.x;
  const int tx = tid & 15, ty = tid >> 4;          // tx: n-quad, ty: m-quad
  const int m0 = blockIdx.x*64, n0 = blockIdx.y*64;
  TACC acc[4][4] = {};
  for (int kt = 0; kt < K; kt += 16) {
    __syncthreads();
    #pragma unroll
    for (int i = 0; i < 4; ++i) {
      const int e = tid + i*256;                   // 0..1023 over [64 rows][16 k]
      const int m = e >> 4, k = e & 15;
      As[k][m] = A[(size_t)(m0+m)*K + kt + k];
      Bs[k][m] = B[(size_t)(n0+m)*K + kt + k];
    }
    __syncthreads();
    #pragma unroll
    for (int k = 0; k < 16; ++k) {
      float av[4], bv[4];
      #pragma unroll
      for (int i = 0; i < 4; ++i) av[i] = As[k][ty*4+i];
      #pragma unroll
      for (int j = 0; j < 4; ++j) bv[j] = Bs[k][tx*4+j];
      #pragma unroll
      for (int i = 0; i < 4; ++i)
        #pragma unroll
        for (int j = 0; j < 4; ++j)
          acc[i][j] += (TACC)av[i] * (TACC)bv[j];
    }
  }
  #pragma unroll
  for (int i = 0; i < 4; ++i)
    #pragma unroll
    for (int j = 0; j < 4; ++j) {
      const size_t off = (size_t)(m0+ty*4+i)*N + n0+tx*4+j;
      if constexpr (OUT == 2) ((double*)C)[off] = (double)acc[i][j];
      else                    ((float*)C)[off]  = (float)acc[i][j];
    }
}

// ---------------- RoPE (f64 in-place) ----------------
__global__ __launch_bounds__(256) void rope_k(double* __restrict__ Q, double* __restrict__ K,
                                              const double2* __restrict__ tab){
  const int idx = blockIdx.x*256 + threadIdx.x;    // (s,h,d2): 2048*32*32
  const int d2 = idx & 31, hh = (idx>>5)&31, s = idx>>10;
  const double2 t = tab[s*32 + d2];
  const double cs = t.x, sn = t.y;
  const size_t base = (size_t)s*2048 + hh*64 + d2;
  const double q1 = Q[base], q2 = Q[base+32];
  const double k1 = K[base], k2 = K[base+32];
  Q[base] = q1*cs - q2*sn; Q[base+32] = q1*sn + q2*cs;
  K[base] = k1*cs - k2*sn; K[base+32] = k1*sn + k2*cs;
}

// ---------------- kmean (f64) ----------------
__global__ __launch_bounds__(64) void kmean_k(const double* __restrict__ Kr,
                                              double* __restrict__ Km){
  const int n = blockIdx.x, h = blockIdx.y, d = threadIdx.x;
  double s = 0.0;
  for (int i = 0; i < 256; ++i) s += Kr[(size_t)(n*256+i)*2048 + h*64 + d];
  Km[(n*32+h)*64 + d] = s * (1.0/256.0);
}

// ---------------- gate + top-4 (f64; tie -> smallest index, matches lax.top_k) ----
__global__ __launch_bounds__(256) void gate_topk_k(const double* __restrict__ Qr,
    const double* __restrict__ Km, unsigned char* __restrict__ Allow){
  const int h = blockIdx.x, c = blockIdx.y, t = threadIdx.x;
  __shared__ double km[512];                       // [8 chunks][64 dims] this head
  km[t]     = Km[((t>>6)*32 + h)*64 + (t&63)];
  km[t+256] = Km[(((t+256)>>6)*32 + h)*64 + (t&63)];
  __syncthreads();
  const int s = c*256 + t;
  const double* qp = Qr + (size_t)s*2048 + h*64;
  double g[8] = {};
  for (int d = 0; d < 64; ++d) {
    const double qv = qp[d];
    #pragma unroll
    for (int n2 = 0; n2 < 8; ++n2) g[n2] += qv*km[n2*64+d];
  }
  #pragma unroll
  for (int n2 = 0; n2 < 8; ++n2) if (n2 > c) g[n2] = -1e300;  // future -> NEG
  g[c] = 1e300;                                               // self -> always picked
  unsigned mask = 0;
  for (int rep = 0; rep < 4; ++rep) {
    double best = -__builtin_inf(); int bi = 0;
    #pragma unroll
    for (int n2 = 0; n2 < 8; ++n2) {
      const bool take = !((mask>>n2)&1u) && (g[n2] > best);
      best = take ? g[n2] : best;
      bi   = take ? n2 : bi;
    }
    mask |= 1u<<bi;
  }
  Allow[h*2048 + s] = (unsigned char)mask;
}

// ---------------- naive fused attention: one 256-thread block per (h, s) ----------------
// scores -> softmax -> PV -> RMSNorm * w * sigmoid(g), f32 throughout.
__global__ __launch_bounds__(256) void attn_naive_k(
    const double* __restrict__ Qd, const double* __restrict__ Kd,
    const float* __restrict__ Vf, const float* __restrict__ Gf,
    const unsigned char* __restrict__ Allow, const float* __restrict__ Wn,
    float* __restrict__ Of)
{
  const int h = blockIdx.x;        // 32
  const int s = blockIdx.y;        // 2048
  const int tid = threadIdx.x;     // 256
  __shared__ float p[2048];
  __shared__ float red[256];
  __shared__ float qs[64];
  __shared__ float ov[256];
  if (tid < 64) qs[tid] = (float)Qd[(size_t)s*2048 + h*64 + tid];
  __syncthreads();
  const unsigned am = Allow[h*2048 + s];
  float lmax = -__builtin_inff();
  float sc[8];
  #pragma unroll
  for (int i = 0; i < 8; ++i) {
    const int t = tid + i*256;
    const bool ok = (t <= s) && ((am >> (t>>8)) & 1u);
    float d = -__builtin_inff();
    if (ok) {
      const double* kp = Kd + (size_t)t*2048 + h*64;
      float acc = 0.f;
      for (int dd = 0; dd < 64; ++dd) acc += qs[dd]*(float)kp[dd];
      d = acc*0.125f;
    }
    sc[i] = d;
    lmax = fmaxf(lmax, d);
  }
  red[tid] = lmax; __syncthreads();
  for (int w = 128; w >= 1; w >>= 1) {
    if (tid < w) red[tid] = fmaxf(red[tid], red[tid+w]);
    __syncthreads();
  }
  const float mx = red[0];
  __syncthreads();
  float lsum = 0.f;
  #pragma unroll
  for (int i = 0; i < 8; ++i) {
    const int t = tid + i*256;
    const float e = __expf(sc[i] - mx);            // exp(-inf)=0 for masked
    p[t] = e;
    lsum += e;
  }
  red[tid] = lsum; __syncthreads();
  for (int w = 128; w >= 1; w >>= 1) {
    if (tid < w) red[tid] += red[tid+w];
    __syncthreads();
  }
  const float linv = 1.0f / red[0];
  __syncthreads();
  const int d = tid & 63, part = tid >> 6;
  float acc = 0.f;
  for (int t = part*512; t < part*512 + 512; ++t)
    acc += p[t] * Vf[(size_t)t*2048 + h*64 + d];
  ov[tid] = acc;
  __syncthreads();
  float o = 0.f;
  if (tid < 64) {
    o = (ov[tid] + ov[tid+64] + ov[tid+128] + ov[tid+192]) * linv;
    red[tid] = o*o;
  }
  __syncthreads();
  if (tid < 32) red[tid] += red[tid+32];
  __syncthreads();
  if (tid < 16) red[tid] += red[tid+16];
  __syncthreads();
  if (tid < 8)  red[tid] += red[tid+8];
  __syncthreads();
  if (tid < 4)  red[tid] += red[tid+4];
  __syncthreads();
  if (tid < 2)  red[tid] += red[tid+2];
  __syncthreads();
  if (tid == 0) red[0] += red[1];
  __syncthreads();
  if (tid < 64) {
    const float rms = rsqrtf(red[0]*(1.0f/64.0f) + 1e-6f);
    const float g = Gf[(size_t)s*2048 + h*64 + tid];
    const float sg = 1.0f/(1.0f + __expf(-g));
    Of[(size_t)s*2048 + h*64 + tid] = o * rms * Wn[tid] * sg;
  }
}

// ---------------- host launch ----------------
extern "C" void kernel_launch(void* const* d_in, const int* in_sizes, int n_in,
                              void* d_out, int out_size, void* d_ws, size_t ws_size,
                              hipStream_t stream)
{
  // F32 device inputs (reference dtype is float32; in_npz 78.66MB confirms).
  const float* hs  = (const float*)d_in[0];
  const float* Wq  = (const float*)d_in[1];
  const float* Wk  = (const float*)d_in[2];
  const float* Wv  = (const float*)d_in[3];
  const float* Wo  = (const float*)d_in[4];
  const float* Wg1 = (const float*)d_in[5];
  const float* Wg2 = (const float*)d_in[6];
  const float* Wn  = (const float*)d_in[7];

  const size_t S2 = (size_t)2048*2048;
  char* ws = (char*)d_ws;
  size_t off = 0;
  auto alloc = [&](size_t b)->void*{ void* p = ws + off; off += (b + 255) & ~(size_t)255; return p; };

  double2* tab = (double2*)alloc((size_t)2048*32*16);
  double* qd = (double*)alloc(S2*8);
  double* kd = (double*)alloc(S2*8);
  float* vf  = (float*)alloc(S2*4);
  float* gf  = (float*)alloc(S2*4);
  float* g1f = (float*)alloc((size_t)2048*64*4);
  double* km = (double*)alloc((size_t)8*32*64*8);
  unsigned char* allow = (unsigned char*)alloc((size_t)32*2048);
  float* of  = (float*)alloc(S2*4);
  (void)ws_size; (void)in_sizes; (void)n_in; (void)out_size;

  rtab_k<<<256,256,0,stream>>>(tab);

  // Q,K projections with f64 accumulation (gate-exactness), z-fused.
  gemm_naive<double,2><<<dim3(32,32,2),256,0,stream>>>(
      hs, Wq, Wk, qd, kd, 2048, 2048, 2048);
  // V projection (f32).
  gemm_naive<float,0><<<dim3(32,32,1),256,0,stream>>>(
      hs, Wv, Wv, vf, vf, 2048, 2048, 2048);
  // gate proj: g1 = hs @ Wg1^T  [2048 x 64], then g = g1 @ Wg2^T [2048 x 2048].
  gemm_naive<float,0><<<dim3(32,1,1),256,0,stream>>>(
      hs, Wg1, Wg1, g1f, g1f, 2048, 64, 2048);
  gemm_naive<float,0><<<dim3(32,32,1),256,0,stream>>>(
      g1f, Wg2, Wg2, gf, gf, 2048, 2048, 64);

  rope_k<<<8192,256,0,stream>>>(qd, kd, tab);
  kmean_k<<<dim3(8,32),64,0,stream>>>(kd, km);
  gate_topk_k<<<dim3(32,8),256,0,stream>>>(qd, km, allow);
  attn_naive_k<<<dim3(32,2048),256,0,stream>>>(qd, kd, vf, gf, allow, Wn, of);

  // Output projection -> FLOAT32 d_out (the R1-R3 bug: was writing bf16).
  gemm_naive<float,0><<<dim3(32,32,1),256,0,stream>>>(
      of, Wo, Wo, d_out, d_out, 2048, 2048, 2048);
}

// Round 7
// 2357.007 us; speedup vs baseline: 3.3013x; 3.3013x over previous
//
#include <hip/hip_runtime.h>
#include <hip/hip_bf16.h>

// MoBA attention, MI355X gfx950 — ROUND 7: green R6 baseline + MFMA flash
// attention (replaces attn_naive_k, was 73% of runtime). Gate path stays f64
// naive (proven green). Attention consumes bf16 Q/K/V^T; f32 epilogue out.

typedef __attribute__((ext_vector_type(8))) short s8v;   // 8 x bf16 = 16B
typedef __attribute__((ext_vector_type(4))) float f4v;   // mfma accumulator

#define MFMA16(A,B,C) __builtin_amdgcn_mfma_f32_16x16x32_bf16(A,B,C,0,0,0)

__device__ __forceinline__ unsigned short f2b_rne(float f){
  unsigned u = __builtin_bit_cast(unsigned, f);
  u = (u + 0x7FFFu + ((u>>16)&1u)) >> 16;
  return (unsigned short)u;
}
__device__ __forceinline__ unsigned pack2(float a, float b){
  return (unsigned)f2b_rne(a) | ((unsigned)f2b_rne(b)<<16);
}

// ---------------- RoPE table: pure f64 phase ----------------
__global__ __launch_bounds__(256) void rtab_k(double2* __restrict__ tab){
  const int i = blockIdx.x*256 + threadIdx.x;      // 2048*32
  if (i >= 2048*32) return;
  const int d2 = i & 31, s = i >> 5;
  const double invf = 1.0 / pow(10000.0, (double)d2 / 32.0);
  const double ph = (double)s * invf;
  tab[i] = make_double2(cos(ph), sin(ph));
}

// ---------------- naive tiled GEMM: C[M,N] = A[M,K] * B[N,K]^T ----------------
// OUT: 0=f32, 2=f64.
template<typename TACC, int OUT>
__global__ __launch_bounds__(256) void gemm_naive(
    const float* __restrict__ A,
    const float* __restrict__ B0, const float* __restrict__ B1,
    void* __restrict__ C0, void* __restrict__ C1,
    int M, int N, int K)
{
  __shared__ float As[16][64];
  __shared__ float Bs[16][64];
  const int z = blockIdx.z;
  const float* B = z ? B1 : B0;
  void* C = z ? C1 : C0;
  const int tid = threadIdx.x;
  const int tx = tid & 15, ty = tid >> 4;
  const int m0 = blockIdx.x*64, n0 = blockIdx.y*64;
  TACC acc[4][4] = {};
  for (int kt = 0; kt < K; kt += 16) {
    __syncthreads();
    #pragma unroll
    for (int i = 0; i < 4; ++i) {
      const int e = tid + i*256;
      const int m = e >> 4, k = e & 15;
      As[k][m] = A[(size_t)(m0+m)*K + kt + k];
      Bs[k][m] = B[(size_t)(n0+m)*K + kt + k];
    }
    __syncthreads();
    #pragma unroll
    for (int k = 0; k < 16; ++k) {
      float av[4], bv[4];
      #pragma unroll
      for (int i = 0; i < 4; ++i) av[i] = As[k][ty*4+i];
      #pragma unroll
      for (int j = 0; j < 4; ++j) bv[j] = Bs[k][tx*4+j];
      #pragma unroll
      for (int i = 0; i < 4; ++i)
        #pragma unroll
        for (int j = 0; j < 4; ++j)
          acc[i][j] += (TACC)av[i] * (TACC)bv[j];
    }
  }
  #pragma unroll
  for (int i = 0; i < 4; ++i)
    #pragma unroll
    for (int j = 0; j < 4; ++j) {
      const size_t off = (size_t)(m0+ty*4+i)*N + n0+tx*4+j;
      if constexpr (OUT == 2) ((double*)C)[off] = (double)acc[i][j];
      else                    ((float*)C)[off]  = (float)acc[i][j];
    }
}

// ---------------- RoPE (f64 in-place) ----------------
__global__ __launch_bounds__(256) void rope_k(double* __restrict__ Q, double* __restrict__ K,
                                              const double2* __restrict__ tab){
  const int idx = blockIdx.x*256 + threadIdx.x;    // (s,h,d2): 2048*32*32
  const int d2 = idx & 31, hh = (idx>>5)&31, s = idx>>10;
  const double2 t = tab[s*32 + d2];
  const double cs = t.x, sn = t.y;
  const size_t base = (size_t)s*2048 + hh*64 + d2;
  const double q1 = Q[base], q2 = Q[base+32];
  const double k1 = K[base], k2 = K[base+32];
  Q[base] = q1*cs - q2*sn; Q[base+32] = q1*sn + q2*cs;
  K[base] = k1*cs - k2*sn; K[base+32] = k1*sn + k2*cs;
}

// ---------------- f64 -> bf16 downcast ----------------
__global__ __launch_bounds__(256) void d2b_k(const double* __restrict__ s,
                                             unsigned short* __restrict__ d, int n){
  const int base = (blockIdx.x*256 + threadIdx.x)*4;
  if (base + 3 < n) {
    #pragma unroll
    for (int j = 0; j < 4; ++j) d[base+j] = f2b_rne((float)s[base+j]);
  } else {
    for (int j = base; j < n; ++j) d[j] = f2b_rne((float)s[j]);
  }
}

// ---------------- kmean (f64) ----------------
__global__ __launch_bounds__(64) void kmean_k(const double* __restrict__ Kr,
                                              double* __restrict__ Km){
  const int n = blockIdx.x, h = blockIdx.y, d = threadIdx.x;
  double s = 0.0;
  for (int i = 0; i < 256; ++i) s += Kr[(size_t)(n*256+i)*2048 + h*64 + d];
  Km[(n*32+h)*64 + d] = s * (1.0/256.0);
}

// ---------------- gate + top-4 (f64; tie -> smallest index) ----------------
__global__ __launch_bounds__(256) void gate_topk_k(const double* __restrict__ Qr,
    const double* __restrict__ Km, unsigned char* __restrict__ Allow){
  const int h = blockIdx.x, c = blockIdx.y, t = threadIdx.x;
  __shared__ double km[512];
  km[t]     = Km[((t>>6)*32 + h)*64 + (t&63)];
  km[t+256] = Km[(((t+256)>>6)*32 + h)*64 + (t&63)];
  __syncthreads();
  const int s = c*256 + t;
  const double* qp = Qr + (size_t)s*2048 + h*64;
  double g[8] = {};
  for (int d = 0; d < 64; ++d) {
    const double qv = qp[d];
    #pragma unroll
    for (int n2 = 0; n2 < 8; ++n2) g[n2] += qv*km[n2*64+d];
  }
  #pragma unroll
  for (int n2 = 0; n2 < 8; ++n2) if (n2 > c) g[n2] = -1e300;
  g[c] = 1e300;
  unsigned mask = 0;
  for (int rep = 0; rep < 4; ++rep) {
    double best = -__builtin_inf(); int bi = 0;
    #pragma unroll
    for (int n2 = 0; n2 < 8; ++n2) {
      const bool take = !((mask>>n2)&1u) && (g[n2] > best);
      best = take ? g[n2] : best;
      bi   = take ? n2 : bi;
    }
    mask |= 1u<<bi;
  }
  Allow[h*2048 + s] = (unsigned char)mask;
}

// ---------------- V transpose: f32 [S][HD] -> bf16 [HD][S] ----------------
__global__ __launch_bounds__(256) void vtrans_k(const float* __restrict__ V,
                                                unsigned short* __restrict__ Vt){
  __shared__ unsigned short tile[64][68];
  const int s0 = blockIdx.x*64, c0 = blockIdx.y*64;
  const int tx = threadIdx.x & 63, ty = threadIdx.x >> 6;
  #pragma unroll
  for (int rr = 0; rr < 16; ++rr) {
    const int r = ty*16 + rr;
    tile[tx][r] = f2b_rne(V[(size_t)(s0+r)*2048 + c0+tx]);
  }
  __syncthreads();
  #pragma unroll
  for (int rr = 0; rr < 16; ++rr) {
    const int cc = ty*16 + rr;
    Vt[(size_t)(c0+cc)*2048 + s0+tx] = tile[cc][tx];
  }
}

// ---------------- MFMA flash attention: one wave per (head, chunk, 64-q slice) ----
// Swapped QK^T: st = mfma(K,Q) -> per-column (query) softmax, 2-step shuffle
// reduce; P relayout via XOR-swizzled LDS; PV from V^T; fused RMSNorm*sigmoid.
__global__ __launch_bounds__(64) void attn_k(
    const unsigned short* __restrict__ Qb, const unsigned short* __restrict__ Kb,
    const unsigned short* __restrict__ Vt, const float* __restrict__ Gf,
    const unsigned char* __restrict__ Allow, const float* __restrict__ Wn,
    float* __restrict__ Of)
{
  const int h = blockIdx.x, c = blockIdx.y, zb = blockIdx.z;
  const int lane = threadIdx.x, lg = lane>>4, lr = lane&15;
  const int qbase = c*256 + zb*64;
  alignas(16) __shared__ char P[8192];           // P[q][key] bf16, XOR-swizzled rows

  s8v qf[4][2];
  unsigned am[4];
  #pragma unroll
  for (int jq = 0; jq < 4; ++jq) {
    const size_t qrow = (size_t)(qbase + jq*16 + lr);
    qf[jq][0] = *(const s8v*)&Qb[qrow*2048 + h*64 + lg*8];
    qf[jq][1] = *(const s8v*)&Qb[qrow*2048 + h*64 + 32 + lg*8];
    am[jq] = Allow[h*2048 + qrow];
  }
  float mx[4] = {-1e30f,-1e30f,-1e30f,-1e30f};
  float ls[4] = {0,0,0,0};
  f4v ot[4][4] = {};
  const unsigned amAll = am[0]|am[1]|am[2]|am[3];

  for (int n = 0; n <= c; ++n) {
    if (!__ballot((amAll>>n)&1u)) continue;      // no q-row in wave selected chunk n
    #pragma unroll 1
    for (int t4 = 0; t4 < 4; ++t4) {
      const int kb0 = n*256 + t4*64;
      s8v kf[4][2];
      #pragma unroll
      for (int i = 0; i < 4; ++i) {
        const size_t krow = (size_t)(kb0 + i*16 + lr);
        kf[i][0] = *(const s8v*)&Kb[krow*2048 + h*64 + lg*8];
        kf[i][1] = *(const s8v*)&Kb[krow*2048 + h*64 + 32 + lg*8];
      }
      f4v st[4][4];
      #pragma unroll
      for (int i = 0; i < 4; ++i)
        #pragma unroll
        for (int jq = 0; jq < 4; ++jq) {
          f4v zz = {};
          zz = MFMA16(kf[i][0], qf[jq][0], zz);
          st[i][jq] = MFMA16(kf[i][1], qf[jq][1], zz);
        }
      float cm[4] = {-__builtin_inff(),-__builtin_inff(),-__builtin_inff(),-__builtin_inff()};
      #pragma unroll
      for (int jq = 0; jq < 4; ++jq) {
        const int okc = (am[jq]>>n)&1;
        const int q = qbase + jq*16 + lr;
        #pragma unroll
        for (int i = 0; i < 4; ++i)
          #pragma unroll
          for (int r = 0; r < 4; ++r) {
            float v = st[i][jq][r]*0.125f;
            const int key = kb0 + i*16 + lg*4 + r;
            const bool ok = okc && (n != c || key <= q);
            v = ok ? v : -__builtin_inff();
            st[i][jq][r] = v;
            cm[jq] = fmaxf(cm[jq], v);
          }
      }
      #pragma unroll
      for (int jq = 0; jq < 4; ++jq) {
        cm[jq] = fmaxf(cm[jq], __shfl_xor(cm[jq], 16));
        cm[jq] = fmaxf(cm[jq], __shfl_xor(cm[jq], 32));
      }
      float al[4];
      #pragma unroll
      for (int jq = 0; jq < 4; ++jq) {
        const float nm = fmaxf(mx[jq], cm[jq]);
        al[jq] = __expf(mx[jq] - nm);
        mx[jq] = nm;
      }
      float ps[4] = {0,0,0,0};
      #pragma unroll
      for (int jq = 0; jq < 4; ++jq) {
        const int q = jq*16 + lr;
        const int sw = (q&7)<<4;
        #pragma unroll
        for (int i = 0; i < 4; ++i) {
          const float p0 = __expf(st[i][jq][0]-mx[jq]);
          const float p1 = __expf(st[i][jq][1]-mx[jq]);
          const float p2 = __expf(st[i][jq][2]-mx[jq]);
          const float p3 = __expf(st[i][jq][3]-mx[jq]);
          ps[jq] += (p0+p1)+(p2+p3);
          uint2 pk; pk.x = pack2(p0,p1); pk.y = pack2(p2,p3);
          *(uint2*)&P[q*128 + ((i*32 + lg*8) ^ sw)] = pk;
        }
      }
      #pragma unroll
      for (int jq = 0; jq < 4; ++jq) {
        ps[jq] += __shfl_xor(ps[jq], 16);
        ps[jq] += __shfl_xor(ps[jq], 32);
        ls[jq] = ls[jq]*al[jq] + ps[jq];
      }
      #pragma unroll
      for (int jd = 0; jd < 4; ++jd)
        #pragma unroll
        for (int jq = 0; jq < 4; ++jq)
          ot[jd][jq] *= al[jq];
      asm volatile("s_waitcnt lgkmcnt(0)" ::: "memory");   // P writes visible
      __builtin_amdgcn_sched_barrier(0);
      #pragma unroll
      for (int kk = 0; kk < 2; ++kk) {
        s8v vfr[4], pfr[4];
        #pragma unroll
        for (int jd = 0; jd < 4; ++jd)
          vfr[jd] = *(const s8v*)&Vt[(size_t)(h*64 + jd*16 + lr)*2048 + kb0 + kk*32 + lg*8];
        #pragma unroll
        for (int jq = 0; jq < 4; ++jq) {
          const int q = jq*16 + lr;
          pfr[jq] = *(const s8v*)&P[q*128 + ((kk*64 + lg*16) ^ ((q&7)<<4))];
        }
        #pragma unroll
        for (int jd = 0; jd < 4; ++jd)
          #pragma unroll
          for (int jq = 0; jq < 4; ++jq)
            ot[jd][jq] = MFMA16(vfr[jd], pfr[jq], ot[jd][jq]);
      }
      asm volatile("s_waitcnt lgkmcnt(0)" ::: "memory");   // reads done before next writes
      __builtin_amdgcn_sched_barrier(0);
    }
  }
  // epilogue: o/l, RMSNorm over d, * w * sigmoid(g), f32 store
  float inv_[4], ssum[4] = {0,0,0,0}, rmsv[4];
  #pragma unroll
  for (int jq = 0; jq < 4; ++jq) inv_[jq] = 1.0f/ls[jq];
  #pragma unroll
  for (int jd = 0; jd < 4; ++jd)
    #pragma unroll
    for (int jq = 0; jq < 4; ++jq)
      #pragma unroll
      for (int r = 0; r < 4; ++r) {
        const float o = ot[jd][jq][r]*inv_[jq];
        ot[jd][jq][r] = o;
        ssum[jq] += o*o;
      }
  #pragma unroll
  for (int jq = 0; jq < 4; ++jq) {
    float s2 = ssum[jq];
    s2 += __shfl_xor(s2, 16);
    s2 += __shfl_xor(s2, 32);
    rmsv[jq] = rsqrtf(s2*(1.0f/64.0f) + 1e-6f);
  }
  float wv[4][4];
  #pragma unroll
  for (int jd = 0; jd < 4; ++jd) {
    const float4 w4 = *(const float4*)&Wn[jd*16 + lg*4];
    wv[jd][0]=w4.x; wv[jd][1]=w4.y; wv[jd][2]=w4.z; wv[jd][3]=w4.w;
  }
  #pragma unroll
  for (int jq = 0; jq < 4; ++jq) {
    const size_t q = (size_t)(qbase + jq*16 + lr);
    #pragma unroll
    for (int jd = 0; jd < 4; ++jd) {
      const float4 g4 = *(const float4*)&Gf[q*2048 + h*64 + jd*16 + lg*4];
      float4 o4;
      o4.x = ot[jd][jq][0]*rmsv[jq]*wv[jd][0]*(1.0f/(1.0f+__expf(-g4.x)));
      o4.y = ot[jd][jq][1]*rmsv[jq]*wv[jd][1]*(1.0f/(1.0f+__expf(-g4.y)));
      o4.z = ot[jd][jq][2]*rmsv[jq]*wv[jd][2]*(1.0f/(1.0f+__expf(-g4.z)));
      o4.w = ot[jd][jq][3]*rmsv[jq]*wv[jd][3]*(1.0f/(1.0f+__expf(-g4.w)));
      *(float4*)&Of[q*2048 + h*64 + jd*16 + lg*4] = o4;
    }
  }
}

// ---------------- host launch ----------------
extern "C" void kernel_launch(void* const* d_in, const int* in_sizes, int n_in,
                              void* d_out, int out_size, void* d_ws, size_t ws_size,
                              hipStream_t stream)
{
  const float* hs  = (const float*)d_in[0];
  const float* Wq  = (const float*)d_in[1];
  const float* Wk  = (const float*)d_in[2];
  const float* Wv  = (const float*)d_in[3];
  const float* Wo  = (const float*)d_in[4];
  const float* Wg1 = (const float*)d_in[5];
  const float* Wg2 = (const float*)d_in[6];
  const float* Wn  = (const float*)d_in[7];

  const size_t S2 = (size_t)2048*2048;
  const size_t MB = (size_t)1<<20;
  char* ws = (char*)d_ws;
  // fixed layout (peak ~97.6MB, same budget class as green R6's 114MB):
  double2*        tab   = (double2*)       (ws);                   // 1MB
  double*         km    = (double*)        (ws + 1*MB);            // 128KB
  unsigned char*  allow = (unsigned char*) (ws + 1*MB + 131072);   // 64KB
  float*          g1f   = (float*)         (ws + 1*MB + 196608);   // 512KB
  double*         qd    = (double*)        (ws + 2*MB);            // [2,34)
  double*         kd    = (double*)        (ws + 34*MB);           // [34,66)
  float*          vf    = (float*)         (ws + 66*MB);           // [66,82)
  float*          gf    = (float*)         (ws + 82*MB);           // [82,98)
  // phase-2 aliases (written only after their host region is dead):
  unsigned short* kb    = (unsigned short*)(ws + 2*MB);            // in dead qd
  float*          of    = (float*)         (ws + 10*MB);           // in dead qd
  unsigned short* qb    = (unsigned short*)(ws + 34*MB);           // in dead kd
  unsigned short* vt    = (unsigned short*)(ws + 42*MB);           // in dead kd
  (void)ws_size; (void)in_sizes; (void)n_in; (void)out_size;

  rtab_k<<<256,256,0,stream>>>(tab);

  // f64 gate path (unchanged, green): Q,K proj -> rope -> kmean -> top-k.
  gemm_naive<double,2><<<dim3(32,32,2),256,0,stream>>>(
      hs, Wq, Wk, qd, kd, 2048, 2048, 2048);
  rope_k<<<8192,256,0,stream>>>(qd, kd, tab);
  kmean_k<<<dim3(8,32),64,0,stream>>>(kd, km);
  gate_topk_k<<<dim3(32,8),256,0,stream>>>(qd, km, allow);

  // downcasts into dead f64 regions: kb <- kd (into qd base; qd dead after
  // topk... but kb must not clobber qd before its downcast) — ORDER: qb first
  // (reads qd, writes into kd-region AFTER kmean used kd? kd still needed!)
  // Safe order: qb <- qd into kd+? No: kd needed for kb. Do kb <- kd into
  // qd region only AFTER qd fully consumed: qb first would write into kd...
  // Resolution: qb <- qd writes into kd region (kd dead after this? NO).
  // Simplest safe order: (1) kb <- kd written into qd base? qd dead: YES
  // (topk done). kd still intact (kb reads it). (2) qb <- qd... qd now
  // partially overwritten by kb (first 8MB = 1M doubles of qd)! Instead read
  // order: (1) qb <- qd into kd base? kd needed by kb. Deadlock unless qb
  // goes elsewhere: put qb AFTER kb in the dead-kd region: (1) kb <- kd into
  // qd[0,8MB) [qd dead, kd intact]; (2) qb <- qd... qd[0,8MB) now holds kb!
  // qd elements 0..1M f64 = seq rows 0..512 destroyed. FIX: qb reads qd but
  // qd region [2,34): kb occupies [2,10). Place OF at [10,26) (unwritten yet)
  // and qb at [26,34)?? qb needs 8MB = [26,34) overlaps qd rows 1536..2048
  // while reading them. UNSAFE. Final resolution: downcast qb FIRST into the
  // gf region (gf not yet written), then kb into qd region, then vt into kd
  // region. gf is written later by the gate GEMM — so move qb to [42,50) in
  // kd region AFTER kb is done and kd is dead:
  //   (1) kb <- kd  -> qd base [2,10)   (qd dead, kd source intact)
  //   (2) qb <- qd? qd rows 0..512 are clobbered by kb. WRONG.
  // => do qb FIRST from qd into kd region is impossible (kd live)...
  // Correct minimal sequence: qb <- qd into [10,18) of the qd region itself
  // is an overlapping-read hazard. So: use gf region as TEMP for qb (gate
  // GEMMs run AFTER attention inputs are built but BEFORE attn)? gf needed
  // BY attn. Use vf region? vf written by V GEMM later. ORDER:
  //   (1) qb(temp) <- qd   -> vf region [66,74)   (vf unwritten)
  //   (2) kb       <- kd   -> qd base  [2,10)     (qd dead)
  //   (3) V GEMM   -> vf?? would clobber qb(temp). Copy qb to [34,42) after
  //       kb? kd dead only after kb. qb final home [34,42) in dead kd —
  //       d2d copy via kernel. Simpler: keep qb AT [66,74) and place vf at
  //       [74,90), gf at [90,106), of at [10,26). Peak 106MB < 114MB green.
  // Layout finalized below (pointers reassigned).

  unsigned short* qb2 = (unsigned short*)(ws + 66*MB);   // [66,74) qb final
  float*          vf2 = (float*)         (ws + 74*MB);   // [74,90)
  float*          gf2 = (float*)         (ws + 90*MB);   // [90,106)
  d2b_k<<<4096,256,0,stream>>>(qd, qb2, (int)S2);        // qd -> qb (qd dead after)
  d2b_k<<<4096,256,0,stream>>>(kd, kb,  (int)S2);        // kd -> kb into dead qd
  (void)qb; (void)vf; (void)gf;

  // V projection (f32) + transpose to bf16 [HD][S] (vt in dead kd region).
  gemm_naive<float,0><<<dim3(32,32,1),256,0,stream>>>(
      hs, Wv, Wv, vf2, vf2, 2048, 2048, 2048);
  vtrans_k<<<dim3(32,32),256,0,stream>>>(vf2, vt);

  // gate proj: g1 = hs @ Wg1^T, then g = g1 @ Wg2^T (f32).
  gemm_naive<float,0><<<dim3(32,1,1),256,0,stream>>>(
      hs, Wg1, Wg1, g1f, g1f, 2048, 64, 2048);
  gemm_naive<float,0><<<dim3(32,32,1),256,0,stream>>>(
      g1f, Wg2, Wg2, gf2, gf2, 2048, 2048, 64);

  // MFMA flash attention -> f32 of (in dead qd region).
  attn_k<<<dim3(32,8,4),64,0,stream>>>(qb2, kb, vt, gf2, allow, Wn, of);

  // Output projection -> f32 d_out.
  gemm_naive<float,0><<<dim3(32,32,1),256,0,stream>>>(
      of, Wo, Wo, d_out, d_out, 2048, 2048, 2048);
}

// Round 8
// 1170.516 us; speedup vs baseline: 6.6477x; 2.0136x over previous
//
#include <hip/hip_runtime.h>
#include <hip/hip_bf16.h>

// MoBA attention, MI355X gfx950 — ROUND 8.
// f64 kept ONLY where top-k exactness demands it: Q projection + gates.
// K-mean computed via rotation-weighted hs sums (no f64 K GEMM).
// K,V projections: 4-term split-bf16 MFMA (f32-accurate). g1/gate2/Wo: bf16 MFMA.
// Attention: validated R7 MFMA flash kernel (unchanged).

typedef __attribute__((ext_vector_type(8))) short s8v;   // 8 x bf16 = 16B
typedef __attribute__((ext_vector_type(4))) float f4v;   // mfma accumulator

#define MFMA16(A,B,C) __builtin_amdgcn_mfma_f32_16x16x32_bf16(A,B,C,0,0,0)

__device__ __forceinline__ unsigned short f2b_rne(float f){
  unsigned u = __builtin_bit_cast(unsigned, f);
  u = (u + 0x7FFFu + ((u>>16)&1u)) >> 16;
  return (unsigned short)u;
}
__device__ __forceinline__ float b2f(unsigned short h){
  unsigned u = ((unsigned)h)<<16;
  return __builtin_bit_cast(float, u);
}
__device__ __forceinline__ unsigned pack2(float a, float b){
  return (unsigned)f2b_rne(a) | ((unsigned)f2b_rne(b)<<16);
}
__device__ __forceinline__ void gld16(const void* g, void* l){
  __builtin_amdgcn_global_load_lds((const __attribute__((address_space(1))) void*)g,
                                   (__attribute__((address_space(3))) void*)l, 16, 0, 0);
}

// ---------------- RoPE table: pure f64 phase ----------------
__global__ __launch_bounds__(256) void rtab_k(double2* __restrict__ tab){
  const int i = blockIdx.x*256 + threadIdx.x;      // 2048*32
  if (i >= 2048*32) return;
  const int d2 = i & 31, s = i >> 5;
  const double invf = 1.0 / pow(10000.0, (double)d2 / 32.0);
  const double ph = (double)s * invf;
  tab[i] = make_double2(cos(ph), sin(ph));
}

// ---------------- f32 -> bf16 convert ----------------
__global__ __launch_bounds__(256) void f2b4_k(const float* __restrict__ s,
                                              unsigned short* __restrict__ d, int n4){
  int i = blockIdx.x*256 + threadIdx.x;
  if (i >= n4) return;
  const float4 v = *(const float4*)(s + (size_t)i*4);
  uint2 p; p.x = pack2(v.x, v.y); p.y = pack2(v.z, v.w);
  *(uint2*)(d + (size_t)i*4) = p;
}

// ---------------- f32 -> bf16 split (hi + lo residual) ----------------
__global__ __launch_bounds__(256) void f2bs_k(const float* __restrict__ s,
    unsigned short* __restrict__ hi, unsigned short* __restrict__ lo, int n4){
  int i = blockIdx.x*256 + threadIdx.x;
  if (i >= n4) return;
  const float4 v = *(const float4*)(s + (size_t)i*4);
  unsigned short h0 = f2b_rne(v.x), h1 = f2b_rne(v.y), h2 = f2b_rne(v.z), h3 = f2b_rne(v.w);
  uint2 ph; ph.x = (unsigned)h0 | ((unsigned)h1<<16); ph.y = (unsigned)h2 | ((unsigned)h3<<16);
  uint2 pl; pl.x = pack2(v.x - b2f(h0), v.y - b2f(h1));
  pl.y = pack2(v.z - b2f(h2), v.w - b2f(h3));
  *(uint2*)(hi + (size_t)i*4) = ph;
  *(uint2*)(lo + (size_t)i*4) = pl;
}

// ---------------- f64 -> bf16 downcast ----------------
__global__ __launch_bounds__(256) void d2b_k(const double* __restrict__ s,
                                             unsigned short* __restrict__ d, int n){
  const int base = (blockIdx.x*256 + threadIdx.x)*4;
  if (base + 3 < n) {
    #pragma unroll
    for (int j = 0; j < 4; ++j) d[base+j] = f2b_rne((float)s[base+j]);
  } else {
    for (int j = base; j < n; ++j) d[j] = f2b_rne((float)s[j]);
  }
}

// ---------------- naive tiled GEMM (f64 acc), LDS padded [16][65] ----------------
template<typename TACC>
__global__ __launch_bounds__(256) void gemm_naive(
    const float* __restrict__ A, const float* __restrict__ B,
    TACC* __restrict__ C, int M, int N, int K)
{
  __shared__ float As[16][65];   // +1 pad: write bank (k+m)%32, conflict-free
  __shared__ float Bs[16][65];
  const int tid = threadIdx.x;
  const int tx = tid & 15, ty = tid >> 4;
  const int m0 = blockIdx.x*64, n0 = blockIdx.y*64;
  TACC acc[4][4] = {};
  for (int kt = 0; kt < K; kt += 16) {
    __syncthreads();
    #pragma unroll
    for (int i = 0; i < 4; ++i) {
      const int e = tid + i*256;
      const int m = e >> 4, k = e & 15;
      As[k][m] = A[(size_t)(m0+m)*K + kt + k];
      Bs[k][m] = B[(size_t)(n0+m)*K + kt + k];
    }
    __syncthreads();
    #pragma unroll
    for (int k = 0; k < 16; ++k) {
      float av[4], bv[4];
      #pragma unroll
      for (int i = 0; i < 4; ++i) av[i] = As[k][ty*4+i];
      #pragma unroll
      for (int j = 0; j < 4; ++j) bv[j] = Bs[k][tx*4+j];
      #pragma unroll
      for (int i = 0; i < 4; ++i)
        #pragma unroll
        for (int j = 0; j < 4; ++j)
          acc[i][j] += (TACC)av[i] * (TACC)bv[j];
    }
  }
  #pragma unroll
  for (int i = 0; i < 4; ++i)
    #pragma unroll
    for (int j = 0; j < 4; ++j)
      C[(size_t)(m0+ty*4+i)*N + n0+tx*4+j] = acc[i][j];
}

// ---------------- RoPE f64 in-place (Q only) ----------------
__global__ __launch_bounds__(256) void rope_k(double* __restrict__ Q,
                                              const double2* __restrict__ tab){
  const int idx = blockIdx.x*256 + threadIdx.x;    // (s,h,d2): 2048*32*32
  const int d2 = idx & 31, hh = (idx>>5)&31, s = idx>>10;
  const double2 t = tab[s*32 + d2];
  const size_t base = (size_t)s*2048 + hh*64 + d2;
  const double q1 = Q[base], q2 = Q[base+32];
  Q[base] = q1*t.x - q2*t.y; Q[base+32] = q1*t.y + q2*t.x;
}

// ---------------- weighted chunk sums: Ac/As[n][d2][2048] (f64) ----------------
// Ac[n,d2,:] = (1/256) sum_i cos(ph_{n*256+i, d2}) * hs_i   (As with sin)
__global__ __launch_bounds__(256) void wsum_k(const float* __restrict__ hs,
    const double2* __restrict__ tab, double* __restrict__ Ac, double* __restrict__ As){
  const int n = blockIdx.x, d2 = blockIdx.y, tid = threadIdx.x;
  double ac[8] = {}, as_[8] = {};
  for (int i = 0; i < 256; ++i) {
    const int s = n*256 + i;
    const double2 t = tab[s*32 + d2];
    #pragma unroll
    for (int j = 0; j < 8; ++j) {
      const double v = (double)hs[(size_t)s*2048 + j*256 + tid];
      ac[j] += t.x*v; as_[j] += t.y*v;
    }
  }
  const size_t ro = (size_t)(n*32 + d2)*2048;
  #pragma unroll
  for (int j = 0; j < 8; ++j) {
    Ac[ro + j*256 + tid] = ac[j]*(1.0/256.0);
    As[ro + j*256 + tid] = as_[j]*(1.0/256.0);
  }
}

// ---------------- kmean from Ac/As and Wk rows (f64) ----------------
// d<32 : km = Ac[n,d]·Wk(h64+d)    - As[n,d]·Wk(h64+d+32)
// d>=32: km = As[n,d-32]·Wk(h64+d-32) + Ac[n,d-32]·Wk(h64+d)
__global__ __launch_bounds__(64) void kmean2_k(const double* __restrict__ Ac,
    const double* __restrict__ As, const float* __restrict__ Wk,
    double* __restrict__ Km){
  const int n = blockIdx.x, h = blockIdx.y, d = threadIdx.x;
  const int d2 = d & 31;
  const bool hiHalf = d >= 32;
  const double* W1 = (const double*)0;
  const float* wk1 = Wk + (size_t)(h*64 + d2)*2048;       // row h64+d2
  const float* wk2 = Wk + (size_t)(h*64 + d2 + 32)*2048;  // row h64+d2+32
  const double* ac = Ac + (size_t)(n*32 + d2)*2048;
  const double* as_ = As + (size_t)(n*32 + d2)*2048;
  (void)W1;
  double a = 0.0, b = 0.0;
  for (int c = 0; c < 2048; ++c) {
    if (!hiHalf) { a += ac[c]*(double)wk1[c]; b += as_[c]*(double)wk2[c]; }
    else         { a += as_[c]*(double)wk1[c]; b += ac[c]*(double)wk2[c]; }
  }
  Km[(size_t)(n*32 + h)*64 + d] = hiHalf ? (a + b) : (a - b);
}

// ---------------- gate + top-4 (f64; tie -> smallest index) ----------------
__global__ __launch_bounds__(256) void gate_topk_k(const double* __restrict__ Qr,
    const double* __restrict__ Km, unsigned char* __restrict__ Allow){
  const int h = blockIdx.x, c = blockIdx.y, t = threadIdx.x;
  __shared__ double km[512];
  km[t]     = Km[((t>>6)*32 + h)*64 + (t&63)];
  km[t+256] = Km[(((t+256)>>6)*32 + h)*64 + (t&63)];
  __syncthreads();
  const int s = c*256 + t;
  const double* qp = Qr + (size_t)s*2048 + h*64;
  double g[8] = {};
  for (int d = 0; d < 64; ++d) {
    const double qv = qp[d];
    #pragma unroll
    for (int n2 = 0; n2 < 8; ++n2) g[n2] += qv*km[n2*64+d];
  }
  #pragma unroll
  for (int n2 = 0; n2 < 8; ++n2) if (n2 > c) g[n2] = -1e300;
  g[c] = 1e300;
  unsigned mask = 0;
  for (int rep = 0; rep < 4; ++rep) {
    double best = -__builtin_inf(); int bi = 0;
    #pragma unroll
    for (int n2 = 0; n2 < 8; ++n2) {
      const bool take = !((mask>>n2)&1u) && (g[n2] > best);
      best = take ? g[n2] : best;
      bi   = take ? n2 : bi;
    }
    mask |= 1u<<bi;
  }
  Allow[h*2048 + s] = (unsigned char)mask;
}

// ---------------- split-bf16 4-term GEMM: C(f32) = (Ah+Al)(Bh+Bl)^T ----------------
__global__ __launch_bounds__(256) void gemm4_bt(
    const unsigned short* __restrict__ Ah, const unsigned short* __restrict__ Al,
    const unsigned short* __restrict__ Bh0, const unsigned short* __restrict__ Bl0,
    const unsigned short* __restrict__ Bh1, const unsigned short* __restrict__ Bl1,
    float* __restrict__ C0, float* __restrict__ C1, int M, int N, int K)
{
  alignas(16) __shared__ char SAh[16384];
  alignas(16) __shared__ char SAl[16384];
  alignas(16) __shared__ char SBh[16384];
  alignas(16) __shared__ char SBl[16384];
  const int z = blockIdx.z;
  const unsigned short* Bh = z ? Bh1 : Bh0;
  const unsigned short* Bl = z ? Bl1 : Bl0;
  float* C = z ? C1 : C0;
  const int t = threadIdx.x;
  const int wave = t>>6, lane = t&63, lg = lane>>4, lr = lane&15;
  const int wm = wave >> 1, wn = wave & 1;
  const int m0 = blockIdx.x*128, n0 = blockIdx.y*128;
  const unsigned short* Ahb = Ah + (size_t)m0*K;
  const unsigned short* Alb = Al + (size_t)m0*K;
  const unsigned short* Bhb = Bh + (size_t)n0*K;
  const unsigned short* Blb = Bl + (size_t)n0*K;
  f4v acc[4][4] = {};
  #pragma unroll 1
  for (int kt = 0; kt < K; kt += 64) {
    __syncthreads();
    #pragma unroll
    for (int i = 0; i < 4; ++i) {
      const size_t go = (size_t)(i*32 + (t>>3))*K + kt + (t&7)*8;
      gld16(Ahb + go, SAh + i*4096 + wave*1024);
      gld16(Alb + go, SAl + i*4096 + wave*1024);
      gld16(Bhb + go, SBh + i*4096 + wave*1024);
      gld16(Blb + go, SBl + i*4096 + wave*1024);
    }
    __syncthreads();
    #pragma unroll
    for (int kk = 0; kk < 2; ++kk) {
      s8v ah[4], al[4], bh[4], bl[4];
      #pragma unroll
      for (int i = 0; i < 4; ++i) {
        const int ro = (wm*64 + i*16 + lr)*128 + kk*64 + lg*16;
        ah[i] = *(const s8v*)&SAh[ro];
        al[i] = *(const s8v*)&SAl[ro];
      }
      #pragma unroll
      for (int j = 0; j < 4; ++j) {
        const int ro = (wn*64 + j*16 + lr)*128 + kk*64 + lg*16;
        bh[j] = *(const s8v*)&SBh[ro];
        bl[j] = *(const s8v*)&SBl[ro];
      }
      #pragma unroll
      for (int i = 0; i < 4; ++i)
        #pragma unroll
        for (int j = 0; j < 4; ++j) {
          f4v a = acc[i][j];
          a = MFMA16(ah[i], bh[j], a);
          a = MFMA16(ah[i], bl[j], a);
          a = MFMA16(al[i], bh[j], a);
          a = MFMA16(al[i], bl[j], a);
          acc[i][j] = a;
        }
    }
  }
  #pragma unroll
  for (int i = 0; i < 4; ++i)
    #pragma unroll
    for (int j = 0; j < 4; ++j) {
      const int row = m0 + wm*64 + i*16 + lg*4;
      const int col = n0 + wn*64 + j*16 + lr;
      #pragma unroll
      for (int r = 0; r < 4; ++r)
        C[(size_t)(row+r)*N + col] = acc[i][j][r];
    }
}

// ---------------- bf16 MFMA GEMM: C = A(bf16)·B(bf16)^T ----------------
template<int BM, int BN, int WN, bool OUTBF>
__global__ __launch_bounds__(256) void gemm_bt(
    const unsigned short* __restrict__ A, const unsigned short* __restrict__ B,
    void* __restrict__ C, int M, int N, int K)
{
  alignas(16) __shared__ char AsB[BM*128];
  alignas(16) __shared__ char BsB[BN*128];
  const int t = threadIdx.x;
  const int wave = t>>6, lane = t&63, lg = lane>>4, lr = lane&15;
  const int wm = wave / WN, wn = wave % WN;
  const int m0 = blockIdx.x*BM, n0 = blockIdx.y*BN;
  const unsigned short* Ab = A + (size_t)m0*K;
  const unsigned short* Bb = B + (size_t)n0*K;
  f4v acc[4][4] = {};
  #pragma unroll 1
  for (int kt = 0; kt < K; kt += 64) {
    __syncthreads();
    #pragma unroll
    for (int i = 0; i < BM/32; ++i)
      gld16(Ab + (size_t)(i*32 + (t>>3))*K + kt + (t&7)*8, AsB + i*4096 + wave*1024);
    #pragma unroll
    for (int i = 0; i < BN/32; ++i)
      gld16(Bb + (size_t)(i*32 + (t>>3))*K + kt + (t&7)*8, BsB + i*4096 + wave*1024);
    __syncthreads();
    #pragma unroll
    for (int kk = 0; kk < 2; ++kk) {
      s8v af[4], bfr[4];
      #pragma unroll
      for (int i = 0; i < 4; ++i)
        af[i] = *(const s8v*)&AsB[(wm*64 + i*16 + lr)*128 + kk*64 + lg*16];
      #pragma unroll
      for (int j = 0; j < 4; ++j)
        bfr[j] = *(const s8v*)&BsB[(wn*64 + j*16 + lr)*128 + kk*64 + lg*16];
      #pragma unroll
      for (int i = 0; i < 4; ++i)
        #pragma unroll
        for (int j = 0; j < 4; ++j)
          acc[i][j] = MFMA16(af[i], bfr[j], acc[i][j]);
    }
  }
  #pragma unroll
  for (int i = 0; i < 4; ++i)
    #pragma unroll
    for (int j = 0; j < 4; ++j) {
      const int row = m0 + wm*64 + i*16 + lg*4;
      const int col = n0 + wn*64 + j*16 + lr;
      #pragma unroll
      for (int r = 0; r < 4; ++r) {
        if (OUTBF) ((unsigned short*)C)[(size_t)(row+r)*N + col] = f2b_rne(acc[i][j][r]);
        else       ((float*)C)[(size_t)(row+r)*N + col] = acc[i][j][r];
      }
    }
}

// ---------------- RoPE f32 on K, write bf16 ----------------
__global__ __launch_bounds__(256) void rope32_k(const float* __restrict__ Kf,
    unsigned short* __restrict__ Kb, const double2* __restrict__ tab){
  const int idx = blockIdx.x*256 + threadIdx.x;    // (s,h,d2)
  const int d2 = idx & 31, hh = (idx>>5)&31, s = idx>>10;
  const double2 t = tab[s*32 + d2];
  const float cs = (float)t.x, sn = (float)t.y;
  const size_t base = (size_t)s*2048 + hh*64 + d2;
  const float k1 = Kf[base], k2 = Kf[base+32];
  Kb[base]    = f2b_rne(k1*cs - k2*sn);
  Kb[base+32] = f2b_rne(k1*sn + k2*cs);
}

// ---------------- V transpose: f32 [S][HD] -> bf16 [HD][S] ----------------
__global__ __launch_bounds__(256) void vtrans_k(const float* __restrict__ V,
                                                unsigned short* __restrict__ Vt){
  __shared__ unsigned short tile[64][68];
  const int s0 = blockIdx.x*64, c0 = blockIdx.y*64;
  const int tx = threadIdx.x & 63, ty = threadIdx.x >> 6;
  #pragma unroll
  for (int rr = 0; rr < 16; ++rr) {
    const int r = ty*16 + rr;
    tile[tx][r] = f2b_rne(V[(size_t)(s0+r)*2048 + c0+tx]);
  }
  __syncthreads();
  #pragma unroll
  for (int rr = 0; rr < 16; ++rr) {
    const int cc = ty*16 + rr;
    Vt[(size_t)(c0+cc)*2048 + s0+tx] = tile[cc][tx];
  }
}

// ---------------- MFMA flash attention (validated R7) ----------------
__global__ __launch_bounds__(64) void attn_k(
    const unsigned short* __restrict__ Qb, const unsigned short* __restrict__ Kb,
    const unsigned short* __restrict__ Vt, const float* __restrict__ Gf,
    const unsigned char* __restrict__ Allow, const float* __restrict__ Wn,
    float* __restrict__ Of)
{
  const int h = blockIdx.x, c = blockIdx.y, zb = blockIdx.z;
  const int lane = threadIdx.x, lg = lane>>4, lr = lane&15;
  const int qbase = c*256 + zb*64;
  alignas(16) __shared__ char P[8192];

  s8v qf[4][2];
  unsigned am[4];
  #pragma unroll
  for (int jq = 0; jq < 4; ++jq) {
    const size_t qrow = (size_t)(qbase + jq*16 + lr);
    qf[jq][0] = *(const s8v*)&Qb[qrow*2048 + h*64 + lg*8];
    qf[jq][1] = *(const s8v*)&Qb[qrow*2048 + h*64 + 32 + lg*8];
    am[jq] = Allow[h*2048 + qrow];
  }
  float mx[4] = {-1e30f,-1e30f,-1e30f,-1e30f};
  float ls[4] = {0,0,0,0};
  f4v ot[4][4] = {};
  const unsigned amAll = am[0]|am[1]|am[2]|am[3];

  for (int n = 0; n <= c; ++n) {
    if (!__ballot((amAll>>n)&1u)) continue;
    #pragma unroll 1
    for (int t4 = 0; t4 < 4; ++t4) {
      const int kb0 = n*256 + t4*64;
      s8v kf[4][2];
      #pragma unroll
      for (int i = 0; i < 4; ++i) {
        const size_t krow = (size_t)(kb0 + i*16 + lr);
        kf[i][0] = *(const s8v*)&Kb[krow*2048 + h*64 + lg*8];
        kf[i][1] = *(const s8v*)&Kb[krow*2048 + h*64 + 32 + lg*8];
      }
      f4v st[4][4];
      #pragma unroll
      for (int i = 0; i < 4; ++i)
        #pragma unroll
        for (int jq = 0; jq < 4; ++jq) {
          f4v zz = {};
          zz = MFMA16(kf[i][0], qf[jq][0], zz);
          st[i][jq] = MFMA16(kf[i][1], qf[jq][1], zz);
        }
      float cm[4] = {-__builtin_inff(),-__builtin_inff(),-__builtin_inff(),-__builtin_inff()};
      #pragma unroll
      for (int jq = 0; jq < 4; ++jq) {
        const int okc = (am[jq]>>n)&1;
        const int q = qbase + jq*16 + lr;
        #pragma unroll
        for (int i = 0; i < 4; ++i)
          #pragma unroll
          for (int r = 0; r < 4; ++r) {
            float v = st[i][jq][r]*0.125f;
            const int key = kb0 + i*16 + lg*4 + r;
            const bool ok = okc && (n != c || key <= q);
            v = ok ? v : -__builtin_inff();
            st[i][jq][r] = v;
            cm[jq] = fmaxf(cm[jq], v);
          }
      }
      #pragma unroll
      for (int jq = 0; jq < 4; ++jq) {
        cm[jq] = fmaxf(cm[jq], __shfl_xor(cm[jq], 16));
        cm[jq] = fmaxf(cm[jq], __shfl_xor(cm[jq], 32));
      }
      float al[4];
      #pragma unroll
      for (int jq = 0; jq < 4; ++jq) {
        const float nm = fmaxf(mx[jq], cm[jq]);
        al[jq] = __expf(mx[jq] - nm);
        mx[jq] = nm;
      }
      float ps[4] = {0,0,0,0};
      #pragma unroll
      for (int jq = 0; jq < 4; ++jq) {
        const int q = jq*16 + lr;
        const int sw = (q&7)<<4;
        #pragma unroll
        for (int i = 0; i < 4; ++i) {
          const float p0 = __expf(st[i][jq][0]-mx[jq]);
          const float p1 = __expf(st[i][jq][1]-mx[jq]);
          const float p2 = __expf(st[i][jq][2]-mx[jq]);
          const float p3 = __expf(st[i][jq][3]-mx[jq]);
          ps[jq] += (p0+p1)+(p2+p3);
          uint2 pk; pk.x = pack2(p0,p1); pk.y = pack2(p2,p3);
          *(uint2*)&P[q*128 + ((i*32 + lg*8) ^ sw)] = pk;
        }
      }
      #pragma unroll
      for (int jq = 0; jq < 4; ++jq) {
        ps[jq] += __shfl_xor(ps[jq], 16);
        ps[jq] += __shfl_xor(ps[jq], 32);
        ls[jq] = ls[jq]*al[jq] + ps[jq];
      }
      #pragma unroll
      for (int jd = 0; jd < 4; ++jd)
        #pragma unroll
        for (int jq = 0; jq < 4; ++jq)
          ot[jd][jq] *= al[jq];
      asm volatile("s_waitcnt lgkmcnt(0)" ::: "memory");
      __builtin_amdgcn_sched_barrier(0);
      #pragma unroll
      for (int kk = 0; kk < 2; ++kk) {
        s8v vfr[4], pfr[4];
        #pragma unroll
        for (int jd = 0; jd < 4; ++jd)
          vfr[jd] = *(const s8v*)&Vt[(size_t)(h*64 + jd*16 + lr)*2048 + kb0 + kk*32 + lg*8];
        #pragma unroll
        for (int jq = 0; jq < 4; ++jq) {
          const int q = jq*16 + lr;
          pfr[jq] = *(const s8v*)&P[q*128 + ((kk*64 + lg*16) ^ ((q&7)<<4))];
        }
        #pragma unroll
        for (int jd = 0; jd < 4; ++jd)
          #pragma unroll
          for (int jq = 0; jq < 4; ++jq)
            ot[jd][jq] = MFMA16(vfr[jd], pfr[jq], ot[jd][jq]);
      }
      asm volatile("s_waitcnt lgkmcnt(0)" ::: "memory");
      __builtin_amdgcn_sched_barrier(0);
    }
  }
  float inv_[4], ssum[4] = {0,0,0,0}, rmsv[4];
  #pragma unroll
  for (int jq = 0; jq < 4; ++jq) inv_[jq] = 1.0f/ls[jq];
  #pragma unroll
  for (int jd = 0; jd < 4; ++jd)
    #pragma unroll
    for (int jq = 0; jq < 4; ++jq)
      #pragma unroll
      for (int r = 0; r < 4; ++r) {
        const float o = ot[jd][jq][r]*inv_[jq];
        ot[jd][jq][r] = o;
        ssum[jq] += o*o;
      }
  #pragma unroll
  for (int jq = 0; jq < 4; ++jq) {
    float s2 = ssum[jq];
    s2 += __shfl_xor(s2, 16);
    s2 += __shfl_xor(s2, 32);
    rmsv[jq] = rsqrtf(s2*(1.0f/64.0f) + 1e-6f);
  }
  float wv[4][4];
  #pragma unroll
  for (int jd = 0; jd < 4; ++jd) {
    const float4 w4 = *(const float4*)&Wn[jd*16 + lg*4];
    wv[jd][0]=w4.x; wv[jd][1]=w4.y; wv[jd][2]=w4.z; wv[jd][3]=w4.w;
  }
  #pragma unroll
  for (int jq = 0; jq < 4; ++jq) {
    const size_t q = (size_t)(qbase + jq*16 + lr);
    #pragma unroll
    for (int jd = 0; jd < 4; ++jd) {
      const float4 g4 = *(const float4*)&Gf[q*2048 + h*64 + jd*16 + lg*4];
      float4 o4;
      o4.x = ot[jd][jq][0]*rmsv[jq]*wv[jd][0]*(1.0f/(1.0f+__expf(-g4.x)));
      o4.y = ot[jd][jq][1]*rmsv[jq]*wv[jd][1]*(1.0f/(1.0f+__expf(-g4.y)));
      o4.z = ot[jd][jq][2]*rmsv[jq]*wv[jd][2]*(1.0f/(1.0f+__expf(-g4.z)));
      o4.w = ot[jd][jq][3]*rmsv[jq]*wv[jd][3]*(1.0f/(1.0f+__expf(-g4.w)));
      *(float4*)&Of[q*2048 + h*64 + jd*16 + lg*4] = o4;
    }
  }
}

// ---------------- host launch ----------------
extern "C" void kernel_launch(void* const* d_in, const int* in_sizes, int n_in,
                              void* d_out, int out_size, void* d_ws, size_t ws_size,
                              hipStream_t stream)
{
  const float* hs  = (const float*)d_in[0];
  const float* Wq  = (const float*)d_in[1];
  const float* Wk  = (const float*)d_in[2];
  const float* Wv  = (const float*)d_in[3];
  const float* Wo  = (const float*)d_in[4];
  const float* Wg1 = (const float*)d_in[5];
  const float* Wg2 = (const float*)d_in[6];
  const float* Wn  = (const float*)d_in[7];

  const size_t S2 = (size_t)2048*2048;
  const size_t MB = (size_t)1<<20;
  char* ws = (char*)d_ws;
  // static layout, peak 106MB (green R6 proved >=114MB available):
  double2*        tab   = (double2*)       (ws);                   // [0,1)
  unsigned short* hsh   = (unsigned short*)(ws + 1*MB);            // [1,9)
  unsigned short* hsl   = (unsigned short*)(ws + 9*MB);            // [9,17)
  unsigned short* Wkh   = (unsigned short*)(ws + 17*MB);           // [17,25) dead after gemm4
  unsigned short* Wkl   = (unsigned short*)(ws + 25*MB);           // [25,33) dead after gemm4
  unsigned short* Wvh   = (unsigned short*)(ws + 33*MB);           // [33,41) dead after gemm4
  unsigned short* Wvl   = (unsigned short*)(ws + 41*MB);           // [41,49) dead after gemm4
  unsigned short* Wg1b  = (unsigned short*)(ws + 49*MB);           // 256KB
  unsigned short* Wg2b  = (unsigned short*)(ws + 49*MB + 262144);  // 256KB
  unsigned short* g1b   = (unsigned short*)(ws + 49*MB + 524288);  // 256KB
  double*         km    = (double*)        (ws + 49*MB + 786432);  // 128KB
  unsigned char*  allow = (unsigned char*) (ws + 49*MB + 917504);  // 64KB
  double*         Ac    = (double*)        (ws + 50*MB);           // [50,54)
  double*         As    = (double*)        (ws + 54*MB);           // [54,58)
  double*         qd    = (double*)        (ws + 58*MB);           // [58,90) dead after d2b
  float*          vf    = (float*)         (ws + 58*MB);           // [58,74) alias (after qd dead)
  float*          kf    = (float*)         (ws + 74*MB);           // [74,90) alias (after qd dead)
  unsigned short* vt    = (unsigned short*)(ws + 74*MB);           // [74,82) alias (after kf dead)
  float*          gf    = (float*)         (ws + 58*MB);           // [58,74) alias (after vf dead)
  unsigned short* qb    = (unsigned short*)(ws + 90*MB);           // [90,98)
  unsigned short* kb    = (unsigned short*)(ws + 98*MB);           // [98,106)
  float*          of    = (float*)         (ws + 17*MB);           // [17,33) alias (dead Wkh/Wkl)
  unsigned short* ofb   = (unsigned short*)(ws + 33*MB);           // [33,41) alias (dead Wvh)
  unsigned short* Wob   = (unsigned short*)(ws + 41*MB);           // [41,49) alias (dead Wvl)
  (void)ws_size; (void)in_sizes; (void)n_in; (void)out_size;

  rtab_k<<<256,256,0,stream>>>(tab);
  f2bs_k<<<4096,256,0,stream>>>(hs, hsh, hsl, (int)(S2/4));
  f2bs_k<<<4096,256,0,stream>>>(Wk, Wkh, Wkl, (int)(S2/4));
  f2bs_k<<<4096,256,0,stream>>>(Wv, Wvh, Wvl, (int)(S2/4));
  f2b4_k<<<128,256,0,stream>>>(Wg1, Wg1b, 64*2048/4);
  f2b4_k<<<128,256,0,stream>>>(Wg2, Wg2b, 2048*64/4);

  // --- exact f64 gate path: Q proj -> rope -> (wsum/kmean2) -> top-k ---
  gemm_naive<double><<<dim3(32,32),256,0,stream>>>(hs, Wq, qd, 2048, 2048, 2048);
  rope_k<<<8192,256,0,stream>>>(qd, tab);
  wsum_k<<<dim3(8,32),256,0,stream>>>(hs, tab, Ac, As);
  kmean2_k<<<dim3(8,32),64,0,stream>>>(Ac, As, Wk, km);
  gate_topk_k<<<dim3(32,8),256,0,stream>>>(qd, km, allow);
  d2b_k<<<4096,256,0,stream>>>(qd, qb, (int)S2);          // qd dead after this

  // --- split-bf16 K,V projections (f32-accurate), z-fused ---
  gemm4_bt<<<dim3(16,16,2),256,0,stream>>>(hsh, hsl, Wkh, Wkl, Wvh, Wvl,
                                           kf, vf, 2048, 2048, 2048);
  rope32_k<<<8192,256,0,stream>>>(kf, kb, tab);           // kf dead after this
  vtrans_k<<<dim3(32,32),256,0,stream>>>(vf, vt);         // vt in dead kf; vf dead after

  // --- gate activations (bf16 MFMA) ---
  gemm_bt<256,64,1,true><<<dim3(8,1),256,0,stream>>>(hsh, Wg1b, g1b, 2048, 64, 2048);
  gemm_bt<128,128,2,false><<<dim3(16,16),256,0,stream>>>(g1b, Wg2b, gf, 2048, 2048, 64);

  // --- attention (validated) ---
  attn_k<<<dim3(32,8,4),64,0,stream>>>(qb, kb, vt, gf, allow, Wn, of);

  // --- output projection (bf16 MFMA) -> f32 d_out ---
  f2b4_k<<<4096,256,0,stream>>>(of, ofb, (int)(S2/4));
  f2b4_k<<<4096,256,0,stream>>>(Wo, Wob, (int)(S2/4));
  gemm_bt<128,128,2,false><<<dim3(16,16),256,0,stream>>>(ofb, Wob, d_out, 2048, 2048, 2048);
}

// Round 9
// 862.939 us; speedup vs baseline: 9.0172x; 1.3564x over previous
//
#include <hip/hip_runtime.h>
#include <hip/hip_bf16.h>

// MoBA attention, MI355X gfx950 — ROUND 9.
// The 575us f64 Q-GEMM is replaced by: split-bf16 MFMA Q (fused into gemm4
// z=3) -> f64 gates from f32 q -> margin test (3rd vs 4th past gate) ->
// sparse f64 repair of close rows (~100 rows, exact vs golden).
// kmean stays f64-exact (wsum/kmean2). Attention: validated MFMA flash kernel.

typedef __attribute__((ext_vector_type(8))) short s8v;   // 8 x bf16 = 16B
typedef __attribute__((ext_vector_type(4))) float f4v;   // mfma accumulator

#define MFMA16(A,B,C) __builtin_amdgcn_mfma_f32_16x16x32_bf16(A,B,C,0,0,0)

__device__ __forceinline__ unsigned short f2b_rne(float f){
  unsigned u = __builtin_bit_cast(unsigned, f);
  u = (u + 0x7FFFu + ((u>>16)&1u)) >> 16;
  return (unsigned short)u;
}
__device__ __forceinline__ float b2f(unsigned short h){
  unsigned u = ((unsigned)h)<<16;
  return __builtin_bit_cast(float, u);
}
__device__ __forceinline__ unsigned pack2(float a, float b){
  return (unsigned)f2b_rne(a) | ((unsigned)f2b_rne(b)<<16);
}
__device__ __forceinline__ void gld16(const void* g, void* l){
  __builtin_amdgcn_global_load_lds((const __attribute__((address_space(1))) void*)g,
                                   (__attribute__((address_space(3))) void*)l, 16, 0, 0);
}

// ---------------- RoPE table: pure f64 phase ----------------
__global__ __launch_bounds__(256) void rtab_k(double2* __restrict__ tab){
  const int i = blockIdx.x*256 + threadIdx.x;      // 2048*32
  if (i >= 2048*32) return;
  const int d2 = i & 31, s = i >> 5;
  const double invf = 1.0 / pow(10000.0, (double)d2 / 32.0);
  const double ph = (double)s * invf;
  tab[i] = make_double2(cos(ph), sin(ph));
}

// ---------------- f32 -> bf16 convert ----------------
__global__ __launch_bounds__(256) void f2b4_k(const float* __restrict__ s,
                                              unsigned short* __restrict__ d, int n4){
  int i = blockIdx.x*256 + threadIdx.x;
  if (i >= n4) return;
  const float4 v = *(const float4*)(s + (size_t)i*4);
  uint2 p; p.x = pack2(v.x, v.y); p.y = pack2(v.z, v.w);
  *(uint2*)(d + (size_t)i*4) = p;
}

// ---------------- f32 -> bf16 split (hi + lo residual) ----------------
__global__ __launch_bounds__(256) void f2bs_k(const float* __restrict__ s,
    unsigned short* __restrict__ hi, unsigned short* __restrict__ lo, int n4){
  int i = blockIdx.x*256 + threadIdx.x;
  if (i >= n4) return;
  const float4 v = *(const float4*)(s + (size_t)i*4);
  unsigned short h0 = f2b_rne(v.x), h1 = f2b_rne(v.y), h2 = f2b_rne(v.z), h3 = f2b_rne(v.w);
  uint2 ph; ph.x = (unsigned)h0 | ((unsigned)h1<<16); ph.y = (unsigned)h2 | ((unsigned)h3<<16);
  uint2 pl; pl.x = pack2(v.x - b2f(h0), v.y - b2f(h1));
  pl.y = pack2(v.z - b2f(h2), v.w - b2f(h3));
  *(uint2*)(hi + (size_t)i*4) = ph;
  *(uint2*)(lo + (size_t)i*4) = pl;
}

// ---------------- weighted chunk sums: Ac/As[n][d2][2048] (f64) ----------------
__global__ __launch_bounds__(256) void wsum_k(const float* __restrict__ hs,
    const double2* __restrict__ tab, double* __restrict__ Ac, double* __restrict__ As){
  const int n = blockIdx.x, d2 = blockIdx.y, tid = threadIdx.x;
  double ac[8] = {}, as_[8] = {};
  for (int i = 0; i < 256; ++i) {
    const int s = n*256 + i;
    const double2 t = tab[s*32 + d2];
    #pragma unroll
    for (int j = 0; j < 8; ++j) {
      const double v = (double)hs[(size_t)s*2048 + j*256 + tid];
      ac[j] += t.x*v; as_[j] += t.y*v;
    }
  }
  const size_t ro = (size_t)(n*32 + d2)*2048;
  #pragma unroll
  for (int j = 0; j < 8; ++j) {
    Ac[ro + j*256 + tid] = ac[j]*(1.0/256.0);
    As[ro + j*256 + tid] = as_[j]*(1.0/256.0);
  }
}

// ---------------- kmean from Ac/As and Wk rows (f64) ----------------
__global__ __launch_bounds__(64) void kmean2_k(const double* __restrict__ Ac,
    const double* __restrict__ As, const float* __restrict__ Wk,
    double* __restrict__ Km){
  const int n = blockIdx.x, h = blockIdx.y, d = threadIdx.x;
  const int d2 = d & 31;
  const bool hiHalf = d >= 32;
  const float* wk1 = Wk + (size_t)(h*64 + d2)*2048;
  const float* wk2 = Wk + (size_t)(h*64 + d2 + 32)*2048;
  const double* ac = Ac + (size_t)(n*32 + d2)*2048;
  const double* as_ = As + (size_t)(n*32 + d2)*2048;
  double a = 0.0, b = 0.0;
  for (int c = 0; c < 2048; ++c) {
    if (!hiHalf) { a += ac[c]*(double)wk1[c]; b += as_[c]*(double)wk2[c]; }
    else         { a += as_[c]*(double)wk1[c]; b += ac[c]*(double)wk2[c]; }
  }
  Km[(size_t)(n*32 + h)*64 + d] = hiHalf ? (a + b) : (a - b);
}

// ---------------- gates from f32 q + f64 km; top-4 + margin flag ----------------
__global__ __launch_bounds__(256) void gate_topk_k(const float* __restrict__ Qf,
    const double* __restrict__ Km, unsigned char* __restrict__ Allow,
    unsigned char* __restrict__ Flags){
  const int h = blockIdx.x, c = blockIdx.y, t = threadIdx.x;
  __shared__ double km[512];
  km[t]     = Km[((t>>6)*32 + h)*64 + (t&63)];
  km[t+256] = Km[(((t+256)>>6)*32 + h)*64 + (t&63)];
  __syncthreads();
  const int s = c*256 + t;
  const float* qp = Qf + (size_t)s*2048 + h*64;
  double g[8] = {};
  for (int d = 0; d < 64; ++d) {
    const double qv = (double)qp[d];
    #pragma unroll
    for (int n2 = 0; n2 < 8; ++n2) g[n2] += qv*km[n2*64+d];
  }
  // margin among past chunks (n<c): competition for 3 non-self slots
  double margin = 1e300;
  if (c >= 4) {
    unsigned pm = 0;
    double v[4];
    for (int rep = 0; rep < 4; ++rep) {
      double best = -1e308; int bi = 0;
      #pragma unroll
      for (int n2 = 0; n2 < 8; ++n2) {
        const bool take = (n2 < c) && !((pm>>n2)&1u) && (g[n2] > best);
        best = take ? g[n2] : best;
        bi   = take ? n2 : bi;
      }
      v[rep] = best; pm |= 1u<<bi;
    }
    margin = v[2] - v[3];
  }
  Flags[h*2048 + s] = (margin < 1e-3) ? 1 : 0;
  #pragma unroll
  for (int n2 = 0; n2 < 8; ++n2) if (n2 > c) g[n2] = -1e300;
  g[c] = 1e300;
  unsigned mask = 0;
  for (int rep = 0; rep < 4; ++rep) {
    double best = -1e308; int bi = 0;
    #pragma unroll
    for (int n2 = 0; n2 < 8; ++n2) {
      const bool take = !((mask>>n2)&1u) && (g[n2] > best);
      best = take ? g[n2] : best;
      bi   = take ? n2 : bi;
    }
    mask |= 1u<<bi;
  }
  Allow[h*2048 + s] = (unsigned char)mask;
}

// ---------------- sparse f64 repair of flagged rows ----------------
__global__ __launch_bounds__(64) void repair_k(
    const float* __restrict__ hs, const float* __restrict__ Wq,
    const double2* __restrict__ tab, const double* __restrict__ Km,
    const unsigned char* __restrict__ Flags, unsigned char* __restrict__ Allow)
{
  const int s = blockIdx.x, d = threadIdx.x;
  __shared__ double qr[64];
  __shared__ double g8[8];
  for (int h = 0; h < 32; ++h) {
    if (!Flags[h*2048 + s]) continue;          // block-uniform
    const float* hrow = hs + (size_t)s*2048;
    const float* wrow = Wq + (size_t)(h*64 + d)*2048;
    double a0=0,a1=0,a2=0,a3=0;
    for (int k = 0; k < 2048; k += 4) {
      a0 += (double)hrow[k]  *(double)wrow[k];
      a1 += (double)hrow[k+1]*(double)wrow[k+1];
      a2 += (double)hrow[k+2]*(double)wrow[k+2];
      a3 += (double)hrow[k+3]*(double)wrow[k+3];
    }
    qr[d] = (a0+a1)+(a2+a3);
    __syncthreads();
    const double2 t = tab[s*32 + (d&31)];
    const double rot = (d < 32) ? (qr[d]*t.x - qr[d+32]*t.y)
                                : (qr[d-32]*t.y + qr[d]*t.x);
    __syncthreads();
    qr[d] = rot;
    __syncthreads();
    if (d < 8) {
      double g = 0;
      const double* kmp = Km + (size_t)(d*32 + h)*64;
      for (int dd = 0; dd < 64; ++dd) g += qr[dd]*kmp[dd];
      g8[d] = g;
    }
    __syncthreads();
    if (d == 0) {
      const int c = s >> 8;
      double g[8];
      #pragma unroll
      for (int n2 = 0; n2 < 8; ++n2)
        g[n2] = (n2 > c) ? -1e300 : ((n2 == c) ? 1e300 : g8[n2]);
      unsigned mask = 0;
      for (int rep = 0; rep < 4; ++rep) {
        double best = -1e308; int bi = 0;
        #pragma unroll
        for (int n2 = 0; n2 < 8; ++n2) {
          const bool take = !((mask>>n2)&1u) && (g[n2] > best);
          best = take ? g[n2] : best;
          bi   = take ? n2 : bi;
        }
        mask |= 1u<<bi;
      }
      Allow[h*2048 + s] = (unsigned char)mask;
    }
    __syncthreads();
  }
}

// ---------------- split-bf16 4-term GEMM: C(f32) = (Ah+Al)(Bh+Bl)^T, z=3 ----------------
__global__ __launch_bounds__(256) void gemm4_bt(
    const unsigned short* __restrict__ Ah, const unsigned short* __restrict__ Al,
    const unsigned short* __restrict__ Bh0, const unsigned short* __restrict__ Bl0,
    const unsigned short* __restrict__ Bh1, const unsigned short* __restrict__ Bl1,
    const unsigned short* __restrict__ Bh2, const unsigned short* __restrict__ Bl2,
    float* __restrict__ C0, float* __restrict__ C1, float* __restrict__ C2,
    int M, int N, int K)
{
  alignas(16) __shared__ char SAh[16384];
  alignas(16) __shared__ char SAl[16384];
  alignas(16) __shared__ char SBh[16384];
  alignas(16) __shared__ char SBl[16384];
  const int z = blockIdx.z;
  const unsigned short* Bh = (z==0) ? Bh0 : ((z==1) ? Bh1 : Bh2);
  const unsigned short* Bl = (z==0) ? Bl0 : ((z==1) ? Bl1 : Bl2);
  float* C = (z==0) ? C0 : ((z==1) ? C1 : C2);
  const int t = threadIdx.x;
  const int wave = t>>6, lane = t&63, lg = lane>>4, lr = lane&15;
  const int wm = wave >> 1, wn = wave & 1;
  const int m0 = blockIdx.x*128, n0 = blockIdx.y*128;
  const unsigned short* Ahb = Ah + (size_t)m0*K;
  const unsigned short* Alb = Al + (size_t)m0*K;
  const unsigned short* Bhb = Bh + (size_t)n0*K;
  const unsigned short* Blb = Bl + (size_t)n0*K;
  f4v acc[4][4] = {};
  #pragma unroll 1
  for (int kt = 0; kt < K; kt += 64) {
    __syncthreads();
    #pragma unroll
    for (int i = 0; i < 4; ++i) {
      const size_t go = (size_t)(i*32 + (t>>3))*K + kt + (t&7)*8;
      gld16(Ahb + go, SAh + i*4096 + wave*1024);
      gld16(Alb + go, SAl + i*4096 + wave*1024);
      gld16(Bhb + go, SBh + i*4096 + wave*1024);
      gld16(Blb + go, SBl + i*4096 + wave*1024);
    }
    __syncthreads();
    #pragma unroll
    for (int kk = 0; kk < 2; ++kk) {
      s8v ah[4], al[4], bh[4], bl[4];
      #pragma unroll
      for (int i = 0; i < 4; ++i) {
        const int ro = (wm*64 + i*16 + lr)*128 + kk*64 + lg*16;
        ah[i] = *(const s8v*)&SAh[ro];
        al[i] = *(const s8v*)&SAl[ro];
      }
      #pragma unroll
      for (int j = 0; j < 4; ++j) {
        const int ro = (wn*64 + j*16 + lr)*128 + kk*64 + lg*16;
        bh[j] = *(const s8v*)&SBh[ro];
        bl[j] = *(const s8v*)&SBl[ro];
      }
      #pragma unroll
      for (int i = 0; i < 4; ++i)
        #pragma unroll
        for (int j = 0; j < 4; ++j) {
          f4v a = acc[i][j];
          a = MFMA16(ah[i], bh[j], a);
          a = MFMA16(ah[i], bl[j], a);
          a = MFMA16(al[i], bh[j], a);
          a = MFMA16(al[i], bl[j], a);
          acc[i][j] = a;
        }
    }
  }
  #pragma unroll
  for (int i = 0; i < 4; ++i)
    #pragma unroll
    for (int j = 0; j < 4; ++j) {
      const int row = m0 + wm*64 + i*16 + lg*4;
      const int col = n0 + wn*64 + j*16 + lr;
      #pragma unroll
      for (int r = 0; r < 4; ++r)
        C[(size_t)(row+r)*N + col] = acc[i][j][r];
    }
}

// ---------------- bf16 MFMA GEMM: C = A(bf16)·B(bf16)^T ----------------
template<int BM, int BN, int WN, bool OUTBF>
__global__ __launch_bounds__(256) void gemm_bt(
    const unsigned short* __restrict__ A, const unsigned short* __restrict__ B,
    void* __restrict__ C, int M, int N, int K)
{
  alignas(16) __shared__ char AsB[BM*128];
  alignas(16) __shared__ char BsB[BN*128];
  const int t = threadIdx.x;
  const int wave = t>>6, lane = t&63, lg = lane>>4, lr = lane&15;
  const int wm = wave / WN, wn = wave % WN;
  const int m0 = blockIdx.x*BM, n0 = blockIdx.y*BN;
  const unsigned short* Ab = A + (size_t)m0*K;
  const unsigned short* Bb = B + (size_t)n0*K;
  f4v acc[4][4] = {};
  #pragma unroll 1
  for (int kt = 0; kt < K; kt += 64) {
    __syncthreads();
    #pragma unroll
    for (int i = 0; i < BM/32; ++i)
      gld16(Ab + (size_t)(i*32 + (t>>3))*K + kt + (t&7)*8, AsB + i*4096 + wave*1024);
    #pragma unroll
    for (int i = 0; i < BN/32; ++i)
      gld16(Bb + (size_t)(i*32 + (t>>3))*K + kt + (t&7)*8, BsB + i*4096 + wave*1024);
    __syncthreads();
    #pragma unroll
    for (int kk = 0; kk < 2; ++kk) {
      s8v af[4], bfr[4];
      #pragma unroll
      for (int i = 0; i < 4; ++i)
        af[i] = *(const s8v*)&AsB[(wm*64 + i*16 + lr)*128 + kk*64 + lg*16];
      #pragma unroll
      for (int j = 0; j < 4; ++j)
        bfr[j] = *(const s8v*)&BsB[(wn*64 + j*16 + lr)*128 + kk*64 + lg*16];
      #pragma unroll
      for (int i = 0; i < 4; ++i)
        #pragma unroll
        for (int j = 0; j < 4; ++j)
          acc[i][j] = MFMA16(af[i], bfr[j], acc[i][j]);
    }
  }
  #pragma unroll
  for (int i = 0; i < 4; ++i)
    #pragma unroll
    for (int j = 0; j < 4; ++j) {
      const int row = m0 + wm*64 + i*16 + lg*4;
      const int col = n0 + wn*64 + j*16 + lr;
      #pragma unroll
      for (int r = 0; r < 4; ++r) {
        if (OUTBF) ((unsigned short*)C)[(size_t)(row+r)*N + col] = f2b_rne(acc[i][j][r]);
        else       ((float*)C)[(size_t)(row+r)*N + col] = acc[i][j][r];
      }
    }
}

// ---------------- RoPE f32: Q in-place + bf16 out ----------------
__global__ __launch_bounds__(256) void rope32q_k(float* __restrict__ Qf,
    unsigned short* __restrict__ Qb, const double2* __restrict__ tab){
  const int idx = blockIdx.x*256 + threadIdx.x;
  const int d2 = idx & 31, hh = (idx>>5)&31, s = idx>>10;
  const double2 t = tab[s*32 + d2];
  const float cs = (float)t.x, sn = (float)t.y;
  const size_t base = (size_t)s*2048 + hh*64 + d2;
  const float q1 = Qf[base], q2 = Qf[base+32];
  const float o1 = q1*cs - q2*sn, o2 = q1*sn + q2*cs;
  Qf[base] = o1; Qf[base+32] = o2;
  Qb[base] = f2b_rne(o1); Qb[base+32] = f2b_rne(o2);
}

// ---------------- RoPE f32 on K, write bf16 only ----------------
__global__ __launch_bounds__(256) void rope32_k(const float* __restrict__ Kf,
    unsigned short* __restrict__ Kb, const double2* __restrict__ tab){
  const int idx = blockIdx.x*256 + threadIdx.x;
  const int d2 = idx & 31, hh = (idx>>5)&31, s = idx>>10;
  const double2 t = tab[s*32 + d2];
  const float cs = (float)t.x, sn = (float)t.y;
  const size_t base = (size_t)s*2048 + hh*64 + d2;
  const float k1 = Kf[base], k2 = Kf[base+32];
  Kb[base]    = f2b_rne(k1*cs - k2*sn);
  Kb[base+32] = f2b_rne(k1*sn + k2*cs);
}

// ---------------- V transpose: f32 [S][HD] -> bf16 [HD][S] ----------------
__global__ __launch_bounds__(256) void vtrans_k(const float* __restrict__ V,
                                                unsigned short* __restrict__ Vt){
  __shared__ unsigned short tile[64][68];
  const int s0 = blockIdx.x*64, c0 = blockIdx.y*64;
  const int tx = threadIdx.x & 63, ty = threadIdx.x >> 6;
  #pragma unroll
  for (int rr = 0; rr < 16; ++rr) {
    const int r = ty*16 + rr;
    tile[tx][r] = f2b_rne(V[(size_t)(s0+r)*2048 + c0+tx]);
  }
  __syncthreads();
  #pragma unroll
  for (int rr = 0; rr < 16; ++rr) {
    const int cc = ty*16 + rr;
    Vt[(size_t)(c0+cc)*2048 + s0+tx] = tile[cc][tx];
  }
}

// ---------------- MFMA flash attention (validated) ----------------
__global__ __launch_bounds__(64) void attn_k(
    const unsigned short* __restrict__ Qb, const unsigned short* __restrict__ Kb,
    const unsigned short* __restrict__ Vt, const float* __restrict__ Gf,
    const unsigned char* __restrict__ Allow, const float* __restrict__ Wn,
    float* __restrict__ Of)
{
  const int h = blockIdx.x, c = blockIdx.y, zb = blockIdx.z;
  const int lane = threadIdx.x, lg = lane>>4, lr = lane&15;
  const int qbase = c*256 + zb*64;
  alignas(16) __shared__ char P[8192];

  s8v qf[4][2];
  unsigned am[4];
  #pragma unroll
  for (int jq = 0; jq < 4; ++jq) {
    const size_t qrow = (size_t)(qbase + jq*16 + lr);
    qf[jq][0] = *(const s8v*)&Qb[qrow*2048 + h*64 + lg*8];
    qf[jq][1] = *(const s8v*)&Qb[qrow*2048 + h*64 + 32 + lg*8];
    am[jq] = Allow[h*2048 + qrow];
  }
  float mx[4] = {-1e30f,-1e30f,-1e30f,-1e30f};
  float ls[4] = {0,0,0,0};
  f4v ot[4][4] = {};
  const unsigned amAll = am[0]|am[1]|am[2]|am[3];

  for (int n = 0; n <= c; ++n) {
    if (!__ballot((amAll>>n)&1u)) continue;
    #pragma unroll 1
    for (int t4 = 0; t4 < 4; ++t4) {
      const int kb0 = n*256 + t4*64;
      s8v kf[4][2];
      #pragma unroll
      for (int i = 0; i < 4; ++i) {
        const size_t krow = (size_t)(kb0 + i*16 + lr);
        kf[i][0] = *(const s8v*)&Kb[krow*2048 + h*64 + lg*8];
        kf[i][1] = *(const s8v*)&Kb[krow*2048 + h*64 + 32 + lg*8];
      }
      f4v st[4][4];
      #pragma unroll
      for (int i = 0; i < 4; ++i)
        #pragma unroll
        for (int jq = 0; jq < 4; ++jq) {
          f4v zz = {};
          zz = MFMA16(kf[i][0], qf[jq][0], zz);
          st[i][jq] = MFMA16(kf[i][1], qf[jq][1], zz);
        }
      float cm[4] = {-__builtin_inff(),-__builtin_inff(),-__builtin_inff(),-__builtin_inff()};
      #pragma unroll
      for (int jq = 0; jq < 4; ++jq) {
        const int okc = (am[jq]>>n)&1;
        const int q = qbase + jq*16 + lr;
        #pragma unroll
        for (int i = 0; i < 4; ++i)
          #pragma unroll
          for (int r = 0; r < 4; ++r) {
            float v = st[i][jq][r]*0.125f;
            const int key = kb0 + i*16 + lg*4 + r;
            const bool ok = okc && (n != c || key <= q);
            v = ok ? v : -__builtin_inff();
            st[i][jq][r] = v;
            cm[jq] = fmaxf(cm[jq], v);
          }
      }
      #pragma unroll
      for (int jq = 0; jq < 4; ++jq) {
        cm[jq] = fmaxf(cm[jq], __shfl_xor(cm[jq], 16));
        cm[jq] = fmaxf(cm[jq], __shfl_xor(cm[jq], 32));
      }
      float al[4];
      #pragma unroll
      for (int jq = 0; jq < 4; ++jq) {
        const float nm = fmaxf(mx[jq], cm[jq]);
        al[jq] = __expf(mx[jq] - nm);
        mx[jq] = nm;
      }
      float ps[4] = {0,0,0,0};
      #pragma unroll
      for (int jq = 0; jq < 4; ++jq) {
        const int q = jq*16 + lr;
        const int sw = (q&7)<<4;
        #pragma unroll
        for (int i = 0; i < 4; ++i) {
          const float p0 = __expf(st[i][jq][0]-mx[jq]);
          const float p1 = __expf(st[i][jq][1]-mx[jq]);
          const float p2 = __expf(st[i][jq][2]-mx[jq]);
          const float p3 = __expf(st[i][jq][3]-mx[jq]);
          ps[jq] += (p0+p1)+(p2+p3);
          uint2 pk; pk.x = pack2(p0,p1); pk.y = pack2(p2,p3);
          *(uint2*)&P[q*128 + ((i*32 + lg*8) ^ sw)] = pk;
        }
      }
      #pragma unroll
      for (int jq = 0; jq < 4; ++jq) {
        ps[jq] += __shfl_xor(ps[jq], 16);
        ps[jq] += __shfl_xor(ps[jq], 32);
        ls[jq] = ls[jq]*al[jq] + ps[jq];
      }
      #pragma unroll
      for (int jd = 0; jd < 4; ++jd)
        #pragma unroll
        for (int jq = 0; jq < 4; ++jq)
          ot[jd][jq] *= al[jq];
      asm volatile("s_waitcnt lgkmcnt(0)" ::: "memory");
      __builtin_amdgcn_sched_barrier(0);
      #pragma unroll
      for (int kk = 0; kk < 2; ++kk) {
        s8v vfr[4], pfr[4];
        #pragma unroll
        for (int jd = 0; jd < 4; ++jd)
          vfr[jd] = *(const s8v*)&Vt[(size_t)(h*64 + jd*16 + lr)*2048 + kb0 + kk*32 + lg*8];
        #pragma unroll
        for (int jq = 0; jq < 4; ++jq) {
          const int q = jq*16 + lr;
          pfr[jq] = *(const s8v*)&P[q*128 + ((kk*64 + lg*16) ^ ((q&7)<<4))];
        }
        #pragma unroll
        for (int jd = 0; jd < 4; ++jd)
          #pragma unroll
          for (int jq = 0; jq < 4; ++jq)
            ot[jd][jq] = MFMA16(vfr[jd], pfr[jq], ot[jd][jq]);
      }
      asm volatile("s_waitcnt lgkmcnt(0)" ::: "memory");
      __builtin_amdgcn_sched_barrier(0);
    }
  }
  float inv_[4], ssum[4] = {0,0,0,0}, rmsv[4];
  #pragma unroll
  for (int jq = 0; jq < 4; ++jq) inv_[jq] = 1.0f/ls[jq];
  #pragma unroll
  for (int jd = 0; jd < 4; ++jd)
    #pragma unroll
    for (int jq = 0; jq < 4; ++jq)
      #pragma unroll
      for (int r = 0; r < 4; ++r) {
        const float o = ot[jd][jq][r]*inv_[jq];
        ot[jd][jq][r] = o;
        ssum[jq] += o*o;
      }
  #pragma unroll
  for (int jq = 0; jq < 4; ++jq) {
    float s2 = ssum[jq];
    s2 += __shfl_xor(s2, 16);
    s2 += __shfl_xor(s2, 32);
    rmsv[jq] = rsqrtf(s2*(1.0f/64.0f) + 1e-6f);
  }
  float wv[4][4];
  #pragma unroll
  for (int jd = 0; jd < 4; ++jd) {
    const float4 w4 = *(const float4*)&Wn[jd*16 + lg*4];
    wv[jd][0]=w4.x; wv[jd][1]=w4.y; wv[jd][2]=w4.z; wv[jd][3]=w4.w;
  }
  #pragma unroll
  for (int jq = 0; jq < 4; ++jq) {
    const size_t q = (size_t)(qbase + jq*16 + lr);
    #pragma unroll
    for (int jd = 0; jd < 4; ++jd) {
      const float4 g4 = *(const float4*)&Gf[q*2048 + h*64 + jd*16 + lg*4];
      float4 o4;
      o4.x = ot[jd][jq][0]*rmsv[jq]*wv[jd][0]*(1.0f/(1.0f+__expf(-g4.x)));
      o4.y = ot[jd][jq][1]*rmsv[jq]*wv[jd][1]*(1.0f/(1.0f+__expf(-g4.y)));
      o4.z = ot[jd][jq][2]*rmsv[jq]*wv[jd][2]*(1.0f/(1.0f+__expf(-g4.z)));
      o4.w = ot[jd][jq][3]*rmsv[jq]*wv[jd][3]*(1.0f/(1.0f+__expf(-g4.w)));
      *(float4*)&Of[q*2048 + h*64 + jd*16 + lg*4] = o4;
    }
  }
}

// ---------------- host launch ----------------
extern "C" void kernel_launch(void* const* d_in, const int* in_sizes, int n_in,
                              void* d_out, int out_size, void* d_ws, size_t ws_size,
                              hipStream_t stream)
{
  const float* hs  = (const float*)d_in[0];
  const float* Wq  = (const float*)d_in[1];
  const float* Wk  = (const float*)d_in[2];
  const float* Wv  = (const float*)d_in[3];
  const float* Wo  = (const float*)d_in[4];
  const float* Wg1 = (const float*)d_in[5];
  const float* Wg2 = (const float*)d_in[6];
  const float* Wn  = (const float*)d_in[7];

  const size_t S2 = (size_t)2048*2048;
  const size_t MB = (size_t)1<<20;
  char* ws = (char*)d_ws;
  // static layout, peak 114MB (== R6's proven budget):
  double2*        tab   = (double2*)       (ws);                   // [0,1)
  unsigned short* hsh   = (unsigned short*)(ws + 1*MB);            // [1,9)
  unsigned short* hsl   = (unsigned short*)(ws + 9*MB);            // [9,17)
  unsigned short* Wqh   = (unsigned short*)(ws + 17*MB);           // [17,25) dead after gemm4
  unsigned short* Wql   = (unsigned short*)(ws + 25*MB);           // [25,33) dead after gemm4
  unsigned short* Wkh   = (unsigned short*)(ws + 33*MB);           // [33,41) dead after gemm4
  unsigned short* Wkl   = (unsigned short*)(ws + 41*MB);           // [41,49) dead after gemm4
  unsigned short* Wvh   = (unsigned short*)(ws + 49*MB);           // [49,57) dead after gemm4
  unsigned short* Wvl   = (unsigned short*)(ws + 57*MB);           // [57,65) dead after gemm4
  unsigned short* Wg1b  = (unsigned short*)(ws + 65*MB);                    // 256KB
  unsigned short* Wg2b  = (unsigned short*)(ws + 65*MB + 262144);          // 256KB
  unsigned short* g1b   = (unsigned short*)(ws + 65*MB + 524288);          // 256KB
  double*         km    = (double*)        (ws + 65*MB + 786432);          // 128KB
  unsigned char*  allow = (unsigned char*) (ws + 65*MB + 917504);          // 64KB
  unsigned char*  flags = (unsigned char*) (ws + 65*MB + 983040);          // 64KB
  float*          qf    = (float*)         (ws + 66*MB);           // [66,82)
  float*          kf    = (float*)         (ws + 82*MB);           // [82,98) dead after rope32
  float*          vf    = (float*)         (ws + 98*MB);           // [98,114) dead after vtrans
  // phase-2 aliases:
  unsigned short* qb    = (unsigned short*)(ws + 17*MB);           // dead Wqh
  unsigned short* kb    = (unsigned short*)(ws + 25*MB);           // dead Wql
  double*         Ac    = (double*)        (ws + 57*MB);           // dead Wvl lower [57,61)
  double*         As    = (double*)        (ws + 61*MB);           // dead Wvl upper [61,65)
  unsigned short* vt    = (unsigned short*)(ws + 82*MB);           // dead kf lower [82,90)
  float*          gf    = (float*)         (ws + 98*MB);           // dead vf [98,114)
  float*          of    = (float*)         (ws + 33*MB);           // dead Wkh+Wkl [33,49)
  unsigned short* ofb   = (unsigned short*)(ws + 90*MB);           // dead kf upper [90,98)
  unsigned short* Wob   = (unsigned short*)(ws + 66*MB);           // dead qf [66,74)
  (void)ws_size; (void)in_sizes; (void)n_in; (void)out_size;

  rtab_k<<<256,256,0,stream>>>(tab);
  f2bs_k<<<4096,256,0,stream>>>(hs, hsh, hsl, (int)(S2/4));
  f2bs_k<<<4096,256,0,stream>>>(Wq, Wqh, Wql, (int)(S2/4));
  f2bs_k<<<4096,256,0,stream>>>(Wk, Wkh, Wkl, (int)(S2/4));
  f2bs_k<<<4096,256,0,stream>>>(Wv, Wvh, Wvl, (int)(S2/4));
  f2b4_k<<<128,256,0,stream>>>(Wg1, Wg1b, 64*2048/4);
  f2b4_k<<<128,256,0,stream>>>(Wg2, Wg2b, 2048*64/4);

  // Q,K,V projections: split-bf16 (f32-accurate), z-fused.
  gemm4_bt<<<dim3(16,16,3),256,0,stream>>>(hsh, hsl, Wqh, Wql, Wkh, Wkl, Wvh, Wvl,
                                           qf, kf, vf, 2048, 2048, 2048);
  // RoPE: Q in-place f32 (for gates) + bf16; K -> bf16.
  rope32q_k<<<8192,256,0,stream>>>(qf, qb, tab);
  rope32_k<<<8192,256,0,stream>>>(kf, kb, tab);
  vtrans_k<<<dim3(32,32),256,0,stream>>>(vf, vt);

  // exact f64 kmean; gates from f32 q (f64 dots) + margin flags; sparse repair.
  wsum_k<<<dim3(8,32),256,0,stream>>>(hs, tab, Ac, As);
  kmean2_k<<<dim3(8,32),64,0,stream>>>(Ac, As, Wk, km);
  gate_topk_k<<<dim3(32,8),256,0,stream>>>(qf, km, allow, flags);
  repair_k<<<2048,64,0,stream>>>(hs, Wq, tab, km, flags, allow);

  // gate activations (bf16 MFMA).
  gemm_bt<256,64,1,true><<<dim3(8,1),256,0,stream>>>(hsh, Wg1b, g1b, 2048, 64, 2048);
  gemm_bt<128,128,2,false><<<dim3(16,16),256,0,stream>>>(g1b, Wg2b, gf, 2048, 2048, 64);

  // attention (validated).
  attn_k<<<dim3(32,8,4),64,0,stream>>>(qb, kb, vt, gf, allow, Wn, of);

  // output projection (bf16 MFMA) -> f32 d_out.
  f2b4_k<<<4096,256,0,stream>>>(of, ofb, (int)(S2/4));
  f2b4_k<<<4096,256,0,stream>>>(Wo, Wob, (int)(S2/4));
  gemm_bt<128,128,2,false><<<dim3(16,16),256,0,stream>>>(ofb, Wob, d_out, 2048, 2048, 2048);
}